// Round 1
// baseline (5906.863 us; speedup 1.0000x reference)
//
#include <hip/hip_runtime.h>
#include <hip/hip_bf16.h>
#include <math.h>

#define DMODEL 1024
#define DFF    4096
#define NTOK   2560
#define PIN    192
#define SATT   68

__device__ __forceinline__ float gelu_f(float x) {
    const float x3 = x * x * x;
    return 0.5f * x * (1.0f + tanhf(0.7978845608028654f * (x + 0.044715f * x3)));
}

// ---------------- patchify + pre_proj + pos enc (4 tokens per block) ----------------
__global__ __launch_bounds__(256) void patch_pre_kernel(
    const float* __restrict__ f, const float* __restrict__ g,
    const float* __restrict__ preW, const float* __restrict__ preb,
    const float* __restrict__ ppos, const float* __restrict__ fpos,
    float* __restrict__ out) {
    const int s0  = blockIdx.x * 4;
    const int tid = threadIdx.x;
    const int n    = s0 >> 8;         // image index 0..9 (same for the 4 tokens)
    const int pair = n >> 1, t = n & 1;
    const float* src = t ? g : f;

    __shared__ float patch[4][PIN];
    for (int l = tid; l < 4 * PIN; l += 256) {
        const int tok = l / PIN, kk = l - tok * PIN;
        const int pidx = (s0 & 255) + tok;
        const int cc = kk >> 6, a = (kk >> 3) & 7, b = kk & 7;
        const int i = pidx >> 4, j = pidx & 15;
        patch[tok][kk] = src[((size_t)(pair * 3 + cc) * 128 + (i * 8 + a)) * 128 + (j * 8 + b)];
    }
    __syncthreads();

    const int n0 = tid * 4;
    float acc[4][4] = {};
    for (int k = 0; k < PIN; ++k) {
        const float4 w = *(const float4*)(preW + (size_t)k * DMODEL + n0);
#pragma unroll
        for (int tok = 0; tok < 4; ++tok) {
            const float pv = patch[tok][k];
            acc[tok][0] += pv * w.x; acc[tok][1] += pv * w.y;
            acc[tok][2] += pv * w.z; acc[tok][3] += pv * w.w;
        }
    }
    const float4 pb = *(const float4*)(preb + n0);
    const float4 fp = *(const float4*)(fpos + (size_t)n * DMODEL + n0);
#pragma unroll
    for (int tok = 0; tok < 4; ++tok) {
        const int pidx = (s0 & 255) + tok;
        const float4 pp = *(const float4*)(ppos + (size_t)pidx * DMODEL + n0);
        float4 o;
        o.x = acc[tok][0] + pb.x + pp.x + fp.x;
        o.y = acc[tok][1] + pb.y + pp.y + fp.y;
        o.z = acc[tok][2] + pb.z + pp.z + fp.z;
        o.w = acc[tok][3] + pb.w + pp.w + fp.w;
        *(float4*)(out + (size_t)(s0 + tok) * DMODEL + n0) = o;
    }
}

// ---------------- LayerNorm (one 256-thread block per row of 1024) ----------------
__global__ __launch_bounds__(256) void ln_kernel(
    const float* __restrict__ x, const float* __restrict__ gam,
    const float* __restrict__ bet, float* __restrict__ out) {
    const int row = blockIdx.x, tid = threadIdx.x;
    const float* xr = x + (size_t)row * DMODEL;
    const float4 v = *(const float4*)(xr + tid * 4);

    __shared__ float red[4];
    __shared__ float stat[2];

    float s = v.x + v.y + v.z + v.w;
#pragma unroll
    for (int off = 32; off; off >>= 1) s += __shfl_down(s, off, 64);
    if ((tid & 63) == 0) red[tid >> 6] = s;
    __syncthreads();
    if (tid == 0) stat[0] = (red[0] + red[1] + red[2] + red[3]) * (1.0f / DMODEL);
    __syncthreads();
    const float m = stat[0];
    const float dx = v.x - m, dy = v.y - m, dz = v.z - m, dw = v.w - m;
    float ss = dx * dx + dy * dy + dz * dz + dw * dw;
#pragma unroll
    for (int off = 32; off; off >>= 1) ss += __shfl_down(ss, off, 64);
    if ((tid & 63) == 0) red[tid >> 6] = ss;
    __syncthreads();
    if (tid == 0) stat[1] = rsqrtf((red[0] + red[1] + red[2] + red[3]) * (1.0f / DMODEL) + 1e-5f);
    __syncthreads();
    const float rstd = stat[1];

    const float4 gv = *(const float4*)(gam + tid * 4);
    const float4 bv = *(const float4*)(bet + tid * 4);
    float4 o;
    o.x = dx * rstd * gv.x + bv.x;
    o.y = dy * rstd * gv.y + bv.y;
    o.z = dz * rstd * gv.z + bv.z;
    o.w = dw * rstd * gv.w + bv.w;
    *(float4*)(out + (size_t)row * DMODEL + tid * 4) = o;
}

// ---------------- fp32 SGEMM, 128x128 tile, BK=16, 8x8 micro-tile ----------------
// EPI: 0 = C = A*B + bias ; 1 = C = res + A*B + bias ; 2 = C = gelu(A*B + bias)
template <int EPI>
__global__ __launch_bounds__(256) void gemm128(
    const float* __restrict__ A, const float* __restrict__ B,
    const float* __restrict__ bias, const float* __restrict__ res,
    float* __restrict__ C, int M, int N, int K) {
    __shared__ float As[16][128];
    __shared__ float Bs[16][128];
    const int tid = threadIdx.x;
    const int bm = blockIdx.y, bn = blockIdx.x;
    const int tx = tid & 15, ty = tid >> 4;

    float acc[8][8] = {};

    const int am  = tid & 127, ka = (tid >> 7) * 8;   // A: 128 rows x 16 k
    const int bn4 = (tid & 31) * 4, kb = tid >> 5;    // B: 16 k x 128 n
    const float* Ap = A + (size_t)(bm * 128 + am) * K + ka;
    const float* Bp = B + (size_t)kb * N + bn * 128 + bn4;

    for (int kt = 0; kt < K; kt += 16) {
        const float4 a0 = *(const float4*)(Ap);
        const float4 a1 = *(const float4*)(Ap + 4);
        const float4 b0 = *(const float4*)(Bp);
        const float4 b1 = *(const float4*)(Bp + (size_t)8 * N);
        __syncthreads();
        As[ka + 0][am] = a0.x; As[ka + 1][am] = a0.y; As[ka + 2][am] = a0.z; As[ka + 3][am] = a0.w;
        As[ka + 4][am] = a1.x; As[ka + 5][am] = a1.y; As[ka + 6][am] = a1.z; As[ka + 7][am] = a1.w;
        *(float4*)&Bs[kb][bn4]     = b0;
        *(float4*)&Bs[kb + 8][bn4] = b1;
        __syncthreads();
#pragma unroll
        for (int kk = 0; kk < 16; ++kk) {
            float a[8], b[8];
            *(float4*)&a[0] = *(const float4*)&As[kk][ty * 4];
            *(float4*)&a[4] = *(const float4*)&As[kk][64 + ty * 4];
            *(float4*)&b[0] = *(const float4*)&Bs[kk][tx * 4];
            *(float4*)&b[4] = *(const float4*)&Bs[kk][64 + tx * 4];
#pragma unroll
            for (int i = 0; i < 8; ++i)
#pragma unroll
                for (int j = 0; j < 8; ++j)
                    acc[i][j] += a[i] * b[j];
        }
        Ap += 16;
        Bp += (size_t)16 * N;
    }

    const int col0 = bn * 128 + tx * 4;
    const float4 bv0 = *(const float4*)(bias + col0);
    const float4 bv1 = *(const float4*)(bias + col0 + 64);
    const float* bv0p = (const float*)&bv0;
    const float* bv1p = (const float*)&bv1;
#pragma unroll
    for (int ih = 0; ih < 2; ++ih) {
#pragma unroll
        for (int i = 0; i < 4; ++i) {
            const int row = bm * 128 + ih * 64 + ty * 4 + i;
            float o0[4], o1[4];
#pragma unroll
            for (int j = 0; j < 4; ++j) {
                o0[j] = acc[ih * 4 + i][j]     + bv0p[j];
                o1[j] = acc[ih * 4 + i][4 + j] + bv1p[j];
            }
            if (EPI == 1) {
                const float* Rp = res + (size_t)row * N + col0;
                const float4 r0 = *(const float4*)Rp;
                const float4 r1 = *(const float4*)(Rp + 64);
                o0[0] += r0.x; o0[1] += r0.y; o0[2] += r0.z; o0[3] += r0.w;
                o1[0] += r1.x; o1[1] += r1.y; o1[2] += r1.z; o1[3] += r1.w;
            }
            if (EPI == 2) {
#pragma unroll
                for (int j = 0; j < 4; ++j) { o0[j] = gelu_f(o0[j]); o1[j] = gelu_f(o1[j]); }
            }
            float* Cp = C + (size_t)row * N + col0;
            *(float4*)Cp        = make_float4(o0[0], o0[1], o0[2], o0[3]);
            *(float4*)(Cp + 64) = make_float4(o1[0], o1[1], o1[2], o1[3]);
        }
    }
}

// ---------------- fp32 SGEMM, 64x64 tile, BK=16, 4x4 micro-tile ----------------
template <int EPI>
__global__ __launch_bounds__(256) void gemm64k(
    const float* __restrict__ A, const float* __restrict__ B,
    const float* __restrict__ bias, const float* __restrict__ res,
    float* __restrict__ C, int M, int N, int K) {
    __shared__ float As[16][64];
    __shared__ float Bs[16][64];
    const int tid = threadIdx.x;
    const int bm = blockIdx.y, bn = blockIdx.x;
    const int tx = tid & 15, ty = tid >> 4;

    float acc[4][4] = {};

    const int am = tid & 63, ka = (tid >> 6) * 4;   // A: 64 rows x 16 k (float4 along K)
    const int bnn = tid & 63, kb = (tid >> 6) * 4;  // B: 16 k x 64 n (4 scalar rows)
    const float* Ap = A + (size_t)(bm * 64 + am) * K + ka;
    const float* Bp = B + (size_t)kb * N + bn * 64 + bnn;

    for (int kt = 0; kt < K; kt += 16) {
        const float4 a0 = *(const float4*)Ap;
        const float b0 = Bp[0];
        const float b1 = Bp[(size_t)N];
        const float b2 = Bp[(size_t)2 * N];
        const float b3 = Bp[(size_t)3 * N];
        __syncthreads();
        As[ka + 0][am] = a0.x; As[ka + 1][am] = a0.y; As[ka + 2][am] = a0.z; As[ka + 3][am] = a0.w;
        Bs[kb + 0][bnn] = b0; Bs[kb + 1][bnn] = b1; Bs[kb + 2][bnn] = b2; Bs[kb + 3][bnn] = b3;
        __syncthreads();
#pragma unroll
        for (int kk = 0; kk < 16; ++kk) {
            float a[4], b[4];
            *(float4*)&a[0] = *(const float4*)&As[kk][ty * 4];
            *(float4*)&b[0] = *(const float4*)&Bs[kk][tx * 4];
#pragma unroll
            for (int i = 0; i < 4; ++i)
#pragma unroll
                for (int j = 0; j < 4; ++j)
                    acc[i][j] += a[i] * b[j];
        }
        Ap += 16;
        Bp += (size_t)16 * N;
    }

    const int col0 = bn * 64 + tx * 4;
    const float4 bv = *(const float4*)(bias + col0);
    const float* bvp = (const float*)&bv;
#pragma unroll
    for (int i = 0; i < 4; ++i) {
        const int row = bm * 64 + ty * 4 + i;
        float o0[4];
#pragma unroll
        for (int j = 0; j < 4; ++j) o0[j] = acc[i][j] + bvp[j];
        if (EPI == 1) {
            const float4 r0 = *(const float4*)(res + (size_t)row * N + col0);
            o0[0] += r0.x; o0[1] += r0.y; o0[2] += r0.z; o0[3] += r0.w;
        }
        if (EPI == 2) {
#pragma unroll
            for (int j = 0; j < 4; ++j) o0[j] = gelu_f(o0[j]);
        }
        *(float4*)(C + (size_t)row * N + col0) = make_float4(o0[0], o0[1], o0[2], o0[3]);
    }
}

// ---------------- flash attention: 64-query tile, 64-key chunks, online softmax ----------------
__global__ __launch_bounds__(256) void attn_kernel(
    const float* __restrict__ qkv, float* __restrict__ o) {
    const int h  = blockIdx.x;   // 0..15
    const int qb = blockIdx.y;   // 0..39 (64 queries each)
    const int tid = threadIdx.x;
    const int tx = tid & 15, ty = tid >> 4;

    __shared__ float Qs[64][SATT];
    __shared__ float Ks[64][SATT];
    __shared__ float Ss[64][SATT];
    __shared__ float Vs[64][64];
    __shared__ float mrow[64], lrow[64], srow[64];

    {   // load Q tile, pre-scaled by hd^-0.5
        const int d4 = (tid & 15) * 4, q0 = tid >> 4;
#pragma unroll
        for (int r = 0; r < 4; ++r) {
            const int q = q0 + r * 16;
            float4 v = *(const float4*)(qkv + (size_t)(qb * 64 + q) * 3072 + h * 64 + d4);
            v.x *= 0.125f; v.y *= 0.125f; v.z *= 0.125f; v.w *= 0.125f;
            *(float4*)&Qs[q][d4] = v;
        }
    }
    if (tid < 64) { mrow[tid] = -3.0e38f; lrow[tid] = 0.0f; }

    float oacc[4][4] = {};
    const int nch = (qb / 4 + 1) * 4;   // allowed key chunks (block-causal, 256-granular)

    for (int kc = 0; kc < nch; ++kc) {
        __syncthreads();
        {   // load K, V chunk
            const int d4 = (tid & 15) * 4, r0 = tid >> 4;
#pragma unroll
            for (int r = 0; r < 4; ++r) {
                const int kk = r0 + r * 16;
                const float* p = qkv + (size_t)(kc * 64 + kk) * 3072 + h * 64 + d4;
                *(float4*)&Ks[kk][d4] = *(const float4*)(p + 1024);
                *(float4*)&Vs[kk][d4] = *(const float4*)(p + 2048);
            }
        }
        __syncthreads();

        // scores: c[i][j] = dot(Q[ty+16i], K[tx+16j])
        float c[4][4] = {};
#pragma unroll 4
        for (int d4 = 0; d4 < 64; d4 += 4) {
            float a[4][4], b[4][4];
#pragma unroll
            for (int i = 0; i < 4; ++i) *(float4*)a[i] = *(const float4*)&Qs[ty + 16 * i][d4];
#pragma unroll
            for (int j = 0; j < 4; ++j) *(float4*)b[j] = *(const float4*)&Ks[tx + 16 * j][d4];
#pragma unroll
            for (int i = 0; i < 4; ++i)
#pragma unroll
                for (int j = 0; j < 4; ++j)
                    c[i][j] += a[i][0] * b[j][0] + a[i][1] * b[j][1]
                             + a[i][2] * b[j][2] + a[i][3] * b[j][3];
        }
#pragma unroll
        for (int i = 0; i < 4; ++i)
#pragma unroll
            for (int j = 0; j < 4; ++j)
                Ss[ty + 16 * i][tx + 16 * j] = c[i][j];
        __syncthreads();

        if (tid < 64) {   // per-row running max update
            float cm = -3.0e38f;
            for (int k2 = 0; k2 < 64; ++k2) cm = fmaxf(cm, Ss[tid][k2]);
            const float nm = fmaxf(mrow[tid], cm);
            const float sc = __expf(mrow[tid] - nm);
            srow[tid] = sc; mrow[tid] = nm; lrow[tid] *= sc;
        }
        __syncthreads();

        // exponentiate own entries, rescale output accumulator
#pragma unroll
        for (int i = 0; i < 4; ++i) {
            const float mi = mrow[ty + 16 * i];
            const float sc = srow[ty + 16 * i];
#pragma unroll
            for (int j = 0; j < 4; ++j) {
                Ss[ty + 16 * i][tx + 16 * j] = __expf(c[i][j] - mi);
                oacc[i][j] *= sc;
            }
        }
        __syncthreads();

        if (tid < 64) {   // per-row sum accumulate
            float s2 = 0.0f;
            for (int k2 = 0; k2 < 64; ++k2) s2 += Ss[tid][k2];
            lrow[tid] += s2;
        }
        __syncthreads();

        // PV: oacc[i][j] += sum_kk P[q_i][kk] * V[kk][tx*4+j]
#pragma unroll 4
        for (int k4 = 0; k4 < 64; k4 += 4) {
            float pr[4][4], vv[4][4];
#pragma unroll
            for (int i = 0; i < 4; ++i) *(float4*)pr[i] = *(const float4*)&Ss[ty + 16 * i][k4];
#pragma unroll
            for (int t = 0; t < 4; ++t) *(float4*)vv[t] = *(const float4*)&Vs[k4 + t][tx * 4];
#pragma unroll
            for (int i = 0; i < 4; ++i)
#pragma unroll
                for (int j = 0; j < 4; ++j)
                    oacc[i][j] += pr[i][0] * vv[0][j] + pr[i][1] * vv[1][j]
                                + pr[i][2] * vv[2][j] + pr[i][3] * vv[3][j];
        }
    }

#pragma unroll
    for (int i = 0; i < 4; ++i) {
        const float inv = 1.0f / lrow[ty + 16 * i];
        float4 out;
        out.x = oacc[i][0] * inv; out.y = oacc[i][1] * inv;
        out.z = oacc[i][2] * inv; out.w = oacc[i][3] * inv;
        *(float4*)(o + (size_t)(qb * 64 + ty + 16 * i) * DMODEL + h * 64 + tx * 4) = out;
    }
}

// ---------------- output-side gather / scatter ----------------
__global__ __launch_bounds__(256) void gather_f_kernel(
    const float* __restrict__ x, float* __restrict__ ftok) {
    const int r = blockIdx.x;             // 0..1279
    const int pair = r >> 8, pidx = r & 255;
    const int srow = pair * 512 + pidx;   // condition-token rows (n even)
    const int c = threadIdx.x * 4;
    *(float4*)(ftok + (size_t)r * DMODEL + c) = *(const float4*)(x + (size_t)srow * DMODEL + c);
}

__global__ __launch_bounds__(192) void depatch_kernel(
    const float* __restrict__ pbuf, float* __restrict__ out) {
    const int r = blockIdx.x;             // token 0..1279
    const int tid = threadIdx.x;          // 0..191
    const int pair = r >> 8, pidx = r & 255;
    const int i = pidx >> 4, j = pidx & 15;
    const int cc = tid >> 6, a = (tid >> 3) & 7, b = tid & 7;
    out[((size_t)(pair * 3 + cc) * 128 + (i * 8 + a)) * 128 + (j * 8 + b)] =
        pbuf[(size_t)r * PIN + tid];
}

// ---------------- launcher ----------------
extern "C" void kernel_launch(void* const* d_in, const int* in_sizes, int n_in,
                              void* d_out, int out_size, void* d_ws, size_t ws_size,
                              hipStream_t stream) {
    const float* f     = (const float*)d_in[0];
    const float* g     = (const float*)d_in[1];
    const float* preW  = (const float*)d_in[2];
    const float* preb  = (const float*)d_in[3];
    const float* postW = (const float*)d_in[4];
    const float* postb = (const float*)d_in[5];
    const float* ppos  = (const float*)d_in[6];
    const float* fpos  = (const float*)d_in[7];
    const float* Wqkv  = (const float*)d_in[8];
    const float* bqkv  = (const float*)d_in[9];
    const float* Wo    = (const float*)d_in[10];
    const float* bo    = (const float*)d_in[11];
    const float* ln1s  = (const float*)d_in[12];
    const float* ln1b  = (const float*)d_in[13];
    const float* W1    = (const float*)d_in[14];
    const float* b1w   = (const float*)d_in[15];
    const float* W2    = (const float*)d_in[16];
    const float* b2w   = (const float*)d_in[17];
    const float* ln2s  = (const float*)d_in[18];
    const float* ln2b  = (const float*)d_in[19];
    float* out = (float*)d_out;

    float* ws   = (float*)d_ws;
    float* x    = ws;                                  // 2560 x 1024
    float* hbuf = x    + (size_t)NTOK * DMODEL;        // 2560 x 1024
    float* qkv  = hbuf + (size_t)NTOK * DMODEL;        // 2560 x 3072
    float* obuf = qkv  + (size_t)NTOK * 3 * DMODEL;    // 2560 x 1024
    float* act  = obuf + (size_t)NTOK * DMODEL;        // 2560 x 4096
    float* ftok = act  + (size_t)NTOK * DFF;           // 1280 x 1024
    float* pbuf = ftok + (size_t)1280 * DMODEL;        // 1280 x 192

    patch_pre_kernel<<<NTOK / 4, 256, 0, stream>>>(f, g, preW, preb, ppos, fpos, x);

    for (int L = 0; L < 4; ++L) {
        ln_kernel<<<NTOK, 256, 0, stream>>>(x, ln1s + L * DMODEL, ln1b + L * DMODEL, hbuf);
        gemm128<0><<<dim3(3 * DMODEL / 128, NTOK / 128), 256, 0, stream>>>(
            hbuf, Wqkv + (size_t)L * DMODEL * 3 * DMODEL, bqkv + (size_t)L * 3 * DMODEL,
            nullptr, qkv, NTOK, 3 * DMODEL, DMODEL);
        attn_kernel<<<dim3(16, NTOK / 64), 256, 0, stream>>>(qkv, obuf);
        gemm64k<1><<<dim3(DMODEL / 64, NTOK / 64), 256, 0, stream>>>(
            obuf, Wo + (size_t)L * DMODEL * DMODEL, bo + (size_t)L * DMODEL,
            x, x, NTOK, DMODEL, DMODEL);
        ln_kernel<<<NTOK, 256, 0, stream>>>(x, ln2s + L * DMODEL, ln2b + L * DMODEL, hbuf);
        gemm128<2><<<dim3(DFF / 128, NTOK / 128), 256, 0, stream>>>(
            hbuf, W1 + (size_t)L * DMODEL * DFF, b1w + (size_t)L * DFF,
            nullptr, act, NTOK, DFF, DMODEL);
        gemm64k<1><<<dim3(DMODEL / 64, NTOK / 64), 256, 0, stream>>>(
            act, W2 + (size_t)L * DFF * DMODEL, b2w + (size_t)L * DMODEL,
            x, x, NTOK, DMODEL, DFF);
    }

    gather_f_kernel<<<1280, 256, 0, stream>>>(x, ftok);
    gemm64k<0><<<dim3(PIN / 64, 1280 / 64), 256, 0, stream>>>(
        ftok, postW, postb, nullptr, pbuf, 1280, PIN, DMODEL);
    depatch_kernel<<<1280, 192, 0, stream>>>(pbuf, out);
}

// Round 3
// 1865.791 us; speedup vs baseline: 3.1659x; 3.1659x over previous
//
#include <hip/hip_runtime.h>
#include <hip/hip_bf16.h>
#include <math.h>

#define DMODEL 1024
#define DFF    4096
#define NTOK   2560
#define PIN    192

typedef __attribute__((ext_vector_type(8))) __bf16 bf16x8;
typedef __attribute__((ext_vector_type(4))) __bf16 bf16x4;
typedef __attribute__((ext_vector_type(4))) float  f32x4;

#define MFMA16(a, b, c) __builtin_amdgcn_mfma_f32_16x16x32_bf16(a, b, c, 0, 0, 0)

__device__ __forceinline__ float gelu_f(float x) {
    const float x3 = x * x * x;
    return 0.5f * x * (1.0f + tanhf(0.7978845608028654f * (x + 0.044715f * x3)));
}

__device__ __forceinline__ void gload16(const void* g, void* l) {
    __builtin_amdgcn_global_load_lds((const __attribute__((address_space(1))) void*)g,
                                     (__attribute__((address_space(3))) void*)l, 16, 0, 0);
}

__device__ __forceinline__ void split_bf(float v, __bf16& hi, __bf16& lo) {
    hi = (__bf16)v;
    lo = (__bf16)(v - (float)hi);
}

// Split-swizzled activation layout ("SS layout"), used for every GEMM A/B operand:
// row r of K fp32 values -> K/32 blocks of 64 bf16 (128 B). Within a block, eight
// 16 B slots; logical slot sl (0-3 = hi k-chunks, 4-7 = lo k-chunks) stored at
// physical slot sl ^ (r & 7). GEMM stages blocks linearly with global_load_lds and
// reads fragments applying the same XOR -> conflict-free ds_read_b128.

// ---------------- patchify + pre_proj + pos enc (fp32, 4 tokens/block) ----------------
__global__ __launch_bounds__(256) void patch_pre_kernel(
    const float* __restrict__ f, const float* __restrict__ g,
    const float* __restrict__ preW, const float* __restrict__ preb,
    const float* __restrict__ ppos, const float* __restrict__ fpos,
    float* __restrict__ out) {
    const int s0  = blockIdx.x * 4;
    const int tid = threadIdx.x;
    const int n    = s0 >> 8;
    const int pair = n >> 1, t = n & 1;
    const float* src = t ? g : f;

    __shared__ float patch[4][PIN];
    for (int l = tid; l < 4 * PIN; l += 256) {
        const int tok = l / PIN, kk = l - tok * PIN;
        const int pidx = (s0 & 255) + tok;
        const int cc = kk >> 6, a = (kk >> 3) & 7, b = kk & 7;
        const int i = pidx >> 4, j = pidx & 15;
        patch[tok][kk] = src[((size_t)(pair * 3 + cc) * 128 + (i * 8 + a)) * 128 + (j * 8 + b)];
    }
    __syncthreads();

    const int n0 = tid * 4;
    float acc[4][4] = {};
    for (int k = 0; k < PIN; ++k) {
        const float4 w = *(const float4*)(preW + (size_t)k * DMODEL + n0);
#pragma unroll
        for (int tok = 0; tok < 4; ++tok) {
            const float pv = patch[tok][k];
            acc[tok][0] += pv * w.x; acc[tok][1] += pv * w.y;
            acc[tok][2] += pv * w.z; acc[tok][3] += pv * w.w;
        }
    }
    const float4 pb = *(const float4*)(preb + n0);
    const float4 fp = *(const float4*)(fpos + (size_t)n * DMODEL + n0);
#pragma unroll
    for (int tok = 0; tok < 4; ++tok) {
        const int pidx = (s0 & 255) + tok;
        const float4 pp = *(const float4*)(ppos + (size_t)pidx * DMODEL + n0);
        float4 o;
        o.x = acc[tok][0] + pb.x + pp.x + fp.x;
        o.y = acc[tok][1] + pb.y + pp.y + fp.y;
        o.z = acc[tok][2] + pb.z + pp.z + fp.z;
        o.w = acc[tok][3] + pb.w + pp.w + fp.w;
        *(float4*)(out + (size_t)(s0 + tok) * DMODEL + n0) = o;
    }
}

// ---------------- weight prep: W[K][N] fp32 -> WT (SS layout, rows = N) ----------------
__global__ __launch_bounds__(256) void wprep_kernel(
    const float* __restrict__ W, __bf16* __restrict__ WT, int K, int N) {
    const int n0 = blockIdx.x * 32, k0 = blockIdx.y * 32;
    const int tid = threadIdx.x;
    __shared__ float t[32][33];

    {
        const int kl = tid >> 3, nq = (tid & 7) * 4;
        const float4 v = *(const float4*)(W + (size_t)(k0 + kl) * N + n0 + nq);
        t[kl][nq] = v.x; t[kl][nq + 1] = v.y; t[kl][nq + 2] = v.z; t[kl][nq + 3] = v.w;
    }
    __syncthreads();

    const int nl = tid >> 3, kq = (tid & 7) * 4;
    const int n = n0 + nl;
    bf16x4 h4, l4;
#pragma unroll
    for (int i = 0; i < 4; ++i) {
        __bf16 hi, lo;
        split_bf(t[kq + i][nl], hi, lo);
        h4[i] = hi; l4[i] = lo;
    }
    const size_t base = (size_t)n * 2 * K + (size_t)(k0 >> 5) * 64 + (kq & 7);
    const int sl = kq >> 3, key = n & 7;
    *(bf16x4*)&WT[base + (size_t)((sl ^ key) << 3)]       = h4;
    *(bf16x4*)&WT[base + (size_t)(((sl | 4) ^ key) << 3)] = l4;
}

// ---------------- LayerNorm -> SS-layout split bf16 ----------------
__global__ __launch_bounds__(256) void ln_split_kernel(
    const float* __restrict__ x, const float* __restrict__ gam,
    const float* __restrict__ bet, __bf16* __restrict__ o) {
    const int row = blockIdx.x, tid = threadIdx.x;
    const float* xr = x + (size_t)row * DMODEL;
    const float4 v = *(const float4*)(xr + tid * 4);

    __shared__ float red[4];
    __shared__ float stat[2];

    float s = v.x + v.y + v.z + v.w;
#pragma unroll
    for (int off = 32; off; off >>= 1) s += __shfl_down(s, off, 64);
    if ((tid & 63) == 0) red[tid >> 6] = s;
    __syncthreads();
    if (tid == 0) stat[0] = (red[0] + red[1] + red[2] + red[3]) * (1.0f / DMODEL);
    __syncthreads();
    const float m = stat[0];
    const float dx = v.x - m, dy = v.y - m, dz = v.z - m, dw = v.w - m;
    float ss = dx * dx + dy * dy + dz * dz + dw * dw;
#pragma unroll
    for (int off = 32; off; off >>= 1) ss += __shfl_down(ss, off, 64);
    if ((tid & 63) == 0) red[tid >> 6] = ss;
    __syncthreads();
    if (tid == 0) stat[1] = rsqrtf((red[0] + red[1] + red[2] + red[3]) * (1.0f / DMODEL) + 1e-5f);
    __syncthreads();
    const float rstd = stat[1];

    const float4 gv = *(const float4*)(gam + tid * 4);
    const float4 bv = *(const float4*)(bet + tid * 4);
    float ov[4];
    ov[0] = dx * rstd * gv.x + bv.x;
    ov[1] = dy * rstd * gv.y + bv.y;
    ov[2] = dz * rstd * gv.z + bv.z;
    ov[3] = dw * rstd * gv.w + bv.w;

    bf16x4 h4, l4;
#pragma unroll
    for (int i = 0; i < 4; ++i) {
        __bf16 hi, lo;
        split_bf(ov[i], hi, lo);
        h4[i] = hi; l4[i] = lo;
    }
    const int k0 = tid * 4;
    const size_t base = (size_t)row * 2048 + (size_t)(k0 >> 5) * 64 + (k0 & 7);
    const int sl = (k0 >> 3) & 3, key = row & 7;
    *(bf16x4*)&o[base + (size_t)((sl ^ key) << 3)]       = h4;
    *(bf16x4*)&o[base + (size_t)(((sl | 4) ^ key) << 3)] = l4;
}

// ---------------- bf16x3 MFMA GEMM: C = A*B (+bias) [+res | gelu-split | ->bf16] ----------------
// A: SS layout [M][2K]  B: SS layout [N][2K]
// EPI 0: bfout[M][N] = bf16(acc + bias)                 (QKV)
// EPI 1: resout[M][N] += acc + bias                     (O-proj / MLP2 residual)
// EPI 2: bfout = SS-layout split of gelu(acc + bias)    (MLP1)
template <int EPI>
__global__ __launch_bounds__(256) void gemm_mfma(
    const __bf16* __restrict__ A, const __bf16* __restrict__ B,
    const float* __restrict__ bias, float* __restrict__ resout,
    __bf16* __restrict__ bfout, int M, int N, int K) {
    __shared__ __bf16 sm[2][2][128 * 64];
    const int tid = threadIdx.x;
    const int w = tid >> 6, l = tid & 63;
    const int bm = blockIdx.y, bn = blockIdx.x;
    const int mat = w >> 1, half = w & 1;

    const size_t rowBytes = (size_t)K * 4;   // bytes per SS row (2K bf16)
    const char* gsrc = (const char*)(mat ? B : A)
        + (size_t)((mat ? bn : bm) * 128 + half * 64 + (l >> 3)) * rowBytes
        + (size_t)(l & 7) * 16;

    auto STAGE = [&](int buf, int kb) {
        const char* s = gsrc + (size_t)kb * 128;
#pragma unroll
        for (int it = 0; it < 8; ++it)
            gload16(s + (size_t)(it * 8) * rowBytes,
                    (void*)&sm[buf][mat][(size_t)(half * 64 + it * 8) * 64]);
    };

    f32x4 acc[4][4];
#pragma unroll
    for (int i = 0; i < 4; ++i)
#pragma unroll
        for (int j = 0; j < 4; ++j) acc[i][j] = f32x4{0.f, 0.f, 0.f, 0.f};

    const int lr = l & 15, lk = l >> 4;
    const int wr = (w >> 1) * 64, wc = (w & 1) * 64;
    const int nk = K >> 5;

    STAGE(0, 0);
    __syncthreads();

    for (int kb = 0; kb < nk; ++kb) {
        const int buf = kb & 1;
        if (kb + 1 < nk) STAGE(buf ^ 1, kb + 1);

        const __bf16* As = sm[buf][0];
        const __bf16* Bs = sm[buf][1];
        bf16x8 ah[4], al[4], bh[4], bl[4];
#pragma unroll
        for (int i = 0; i < 4; ++i) {
            const int row = wr + i * 16 + lr, kx = row & 7;
            ah[i] = *(const bf16x8*)&As[(size_t)row * 64 + ((lk ^ kx) << 3)];
            al[i] = *(const bf16x8*)&As[(size_t)row * 64 + (((lk | 4) ^ kx) << 3)];
            const int col = wc + i * 16 + lr, ky = col & 7;
            bh[i] = *(const bf16x8*)&Bs[(size_t)col * 64 + ((lk ^ ky) << 3)];
            bl[i] = *(const bf16x8*)&Bs[(size_t)col * 64 + (((lk | 4) ^ ky) << 3)];
        }
#pragma unroll
        for (int i = 0; i < 4; ++i)
#pragma unroll
            for (int j = 0; j < 4; ++j) {
                acc[i][j] = MFMA16(ah[i], bh[j], acc[i][j]);
                acc[i][j] = MFMA16(al[i], bh[j], acc[i][j]);
                acc[i][j] = MFMA16(ah[i], bl[j], acc[i][j]);
            }
        __syncthreads();
    }

#pragma unroll
    for (int j = 0; j < 4; ++j) {
        const int col = bn * 128 + wc + j * 16 + lr;
        const float bv = bias[col];
#pragma unroll
        for (int i = 0; i < 4; ++i) {
#pragma unroll
            for (int r = 0; r < 4; ++r) {
                const int rr = bm * 128 + wr + i * 16 + lk * 4 + r;
                const float v = acc[i][j][r] + bv;
                if (EPI == 0) {
                    bfout[(size_t)rr * N + col] = (__bf16)v;
                } else if (EPI == 1) {
                    const size_t id = (size_t)rr * N + col;
                    resout[id] += v;
                } else {
                    const float gv2 = gelu_f(v);
                    __bf16 hi, lo;
                    split_bf(gv2, hi, lo);
                    const size_t base = (size_t)rr * 2 * N + (size_t)(col >> 5) * 64 + (col & 7);
                    const int sl = (col >> 3) & 3, kx = rr & 7;
                    bfout[base + (size_t)((sl ^ kx) << 3)]       = hi;
                    bfout[base + (size_t)(((sl | 4) ^ kx) << 3)] = lo;
                }
            }
        }
    }
}

// ---------------- flash attention, bf16 MFMA 16x16x32, 4 waves x 16 queries ----------------
__global__ __launch_bounds__(256) void attn_mfma(
    const __bf16* __restrict__ qkv, __bf16* __restrict__ o) {
    const int h  = blockIdx.x;
    const int qb = blockIdx.y;
    const int tid = threadIdx.x;
    const int w = tid >> 6, l = tid & 63;
    const int lr = l & 15, lk = l >> 4;

    __shared__ __bf16 Ks[64 * 64];
    __shared__ __bf16 Vt[64 * 64];
    __shared__ __bf16 Ps[4][16 * 64];

    // Q fragments (row = query, k = d)
    const int qrow = qb * 64 + w * 16 + lr;
    const __bf16* qsrc = qkv + (size_t)qrow * 3072 + h * 64 + lk * 8;
    const bf16x8 qf0 = *(const bf16x8*)qsrc;
    const bf16x8 qf1 = *(const bf16x8*)(qsrc + 32);

    f32x4 oacc[4];
#pragma unroll
    for (int i = 0; i < 4; ++i) oacc[i] = f32x4{0.f, 0.f, 0.f, 0.f};
    float mrow[4], lrow[4];
#pragma unroll
    for (int r = 0; r < 4; ++r) { mrow[r] = -3.0e38f; lrow[r] = 0.f; }

    const int skey = tid >> 2, dc = (tid & 3) * 16;   // staging assignment
    const int nch = ((qb >> 2) + 1) * 4;

    for (int kc = 0; kc < nch; ++kc) {
        __syncthreads();
        {   // stage K (swizzled [key][d]) and V^T (swizzled [d][key])
            const __bf16* kp = qkv + (size_t)(kc * 64 + skey) * 3072 + 1024 + h * 64 + dc;
            const bf16x8 k0 = *(const bf16x8*)kp;
            const bf16x8 k1 = *(const bf16x8*)(kp + 8);
            const int sl0 = dc >> 3;
            *(bf16x8*)&Ks[skey * 64 + ((sl0 ^ (skey & 7)) << 3)]       = k0;
            *(bf16x8*)&Ks[skey * 64 + (((sl0 | 1) ^ (skey & 7)) << 3)] = k1;

            const __bf16* vp = kp + 1024;
            const bf16x8 v0 = *(const bf16x8*)vp;
            const bf16x8 v1 = *(const bf16x8*)(vp + 8);
#pragma unroll
            for (int e = 0; e < 8; ++e) {
                const int d0 = dc + e, d1 = dc + 8 + e;
                Vt[d0 * 64 + (((skey >> 3) ^ (d0 & 7)) << 3) + (skey & 7)] = v0[e];
                Vt[d1 * 64 + (((skey >> 3) ^ (d1 & 7)) << 3) + (skey & 7)] = v1[e];
            }
        }
        __syncthreads();

        // QK^T
        f32x4 sv[4];
#pragma unroll
        for (int j = 0; j < 4; ++j) {
            sv[j] = f32x4{0.f, 0.f, 0.f, 0.f};
            const int kb = j * 16 + lr, sw = kb & 7;
            const bf16x8 kb0 = *(const bf16x8*)&Ks[kb * 64 + ((lk ^ sw) << 3)];
            const bf16x8 kb1 = *(const bf16x8*)&Ks[kb * 64 + (((lk | 4) ^ sw) << 3)];
            sv[j] = MFMA16(qf0, kb0, sv[j]);
            sv[j] = MFMA16(qf1, kb1, sv[j]);
        }

        // online softmax (C layout: row = lk*4+r, col = j*16+lr)
#pragma unroll
        for (int r = 0; r < 4; ++r) {
            float cm = fmaxf(fmaxf(sv[0][r], sv[1][r]), fmaxf(sv[2][r], sv[3][r])) * 0.125f;
#pragma unroll
            for (int msk = 1; msk < 16; msk <<= 1) cm = fmaxf(cm, __shfl_xor(cm, msk, 64));
            const float nm = fmaxf(mrow[r], cm);
            const float sc = __expf(mrow[r] - nm);
            float rs = 0.f;
#pragma unroll
            for (int j = 0; j < 4; ++j) {
                const float p = __expf(sv[j][r] * 0.125f - nm);
                sv[j][r] = p;
                rs += p;
            }
#pragma unroll
            for (int msk = 1; msk < 16; msk <<= 1) rs += __shfl_xor(rs, msk, 64);
            lrow[r] = lrow[r] * sc + rs;
            mrow[r] = nm;
#pragma unroll
            for (int db = 0; db < 4; ++db) oacc[db][r] *= sc;
        }

        // P -> per-wave LDS (swizzled [q][key]); same-wave in-order DS, no barrier
#pragma unroll
        for (int j = 0; j < 4; ++j)
#pragma unroll
            for (int r = 0; r < 4; ++r) {
                const int q = lk * 4 + r, key = j * 16 + lr;
                Ps[w][q * 64 + (((key >> 3) ^ (q & 7)) << 3) + (key & 7)] = (__bf16)sv[j][r];
            }
        asm volatile("" ::: "memory");

        // PV
#pragma unroll
        for (int db = 0; db < 4; ++db) {
            const int d = db * 16 + lr, dw2 = d & 7;
#pragma unroll
            for (int kk = 0; kk < 2; ++kk) {
                const int sl = kk * 4 + lk;
                const bf16x8 pa = *(const bf16x8*)&Ps[w][lr * 64 + ((sl ^ (lr & 7)) << 3)];
                const bf16x8 vb = *(const bf16x8*)&Vt[d * 64 + ((sl ^ dw2) << 3)];
                oacc[db] = MFMA16(pa, vb, oacc[db]);
            }
        }
    }

    float inv[4];
#pragma unroll
    for (int r = 0; r < 4; ++r) inv[r] = 1.0f / lrow[r];

#pragma unroll
    for (int db = 0; db < 4; ++db)
#pragma unroll
        for (int r = 0; r < 4; ++r) {
            const float v = oacc[db][r] * inv[r];
            const int rr = qb * 64 + w * 16 + lk * 4 + r;
            const int col = h * 64 + db * 16 + lr;
            __bf16 hi, lo;
            split_bf(v, hi, lo);
            const size_t base = (size_t)rr * 2048 + (size_t)(col >> 5) * 64 + (col & 7);
            const int sl = (col >> 3) & 3, kx = rr & 7;
            o[base + (size_t)((sl ^ kx) << 3)]       = hi;
            o[base + (size_t)(((sl | 4) ^ kx) << 3)] = lo;
        }
}

// ---------------- fp32 SGEMM 64x64 (post-proj only) ----------------
template <int EPI>
__global__ __launch_bounds__(256) void gemm64k(
    const float* __restrict__ A, const float* __restrict__ B,
    const float* __restrict__ bias, const float* __restrict__ res,
    float* __restrict__ C, int M, int N, int K) {
    __shared__ float As[16][64];
    __shared__ float Bs[16][64];
    const int tid = threadIdx.x;
    const int bm = blockIdx.y, bn = blockIdx.x;
    const int tx = tid & 15, ty = tid >> 4;

    float acc[4][4] = {};

    const int am = tid & 63, ka = (tid >> 6) * 4;
    const int bnn = tid & 63, kb = (tid >> 6) * 4;
    const float* Ap = A + (size_t)(bm * 64 + am) * K + ka;
    const float* Bp = B + (size_t)kb * N + bn * 64 + bnn;

    for (int kt = 0; kt < K; kt += 16) {
        const float4 a0 = *(const float4*)Ap;
        const float b0 = Bp[0];
        const float b1 = Bp[(size_t)N];
        const float b2 = Bp[(size_t)2 * N];
        const float b3 = Bp[(size_t)3 * N];
        __syncthreads();
        As[ka + 0][am] = a0.x; As[ka + 1][am] = a0.y; As[ka + 2][am] = a0.z; As[ka + 3][am] = a0.w;
        Bs[kb + 0][bnn] = b0; Bs[kb + 1][bnn] = b1; Bs[kb + 2][bnn] = b2; Bs[kb + 3][bnn] = b3;
        __syncthreads();
#pragma unroll
        for (int kk = 0; kk < 16; ++kk) {
            float a[4], b[4];
            *(float4*)&a[0] = *(const float4*)&As[kk][ty * 4];
            *(float4*)&b[0] = *(const float4*)&Bs[kk][tx * 4];
#pragma unroll
            for (int i = 0; i < 4; ++i)
#pragma unroll
                for (int j = 0; j < 4; ++j)
                    acc[i][j] += a[i] * b[j];
        }
        Ap += 16;
        Bp += (size_t)16 * N;
    }

    const int col0 = bn * 64 + tx * 4;
    const float4 bv = *(const float4*)(bias + col0);
    const float* bvp = (const float*)&bv;
#pragma unroll
    for (int i = 0; i < 4; ++i) {
        const int row = bm * 64 + ty * 4 + i;
        float o0[4];
#pragma unroll
        for (int j = 0; j < 4; ++j) o0[j] = acc[i][j] + bvp[j];
        if (EPI == 1) {
            const float4 r0 = *(const float4*)(res + (size_t)row * N + col0);
            o0[0] += r0.x; o0[1] += r0.y; o0[2] += r0.z; o0[3] += r0.w;
        }
        *(float4*)(C + (size_t)row * N + col0) = make_float4(o0[0], o0[1], o0[2], o0[3]);
    }
}

// ---------------- output-side gather / scatter ----------------
__global__ __launch_bounds__(256) void gather_f_kernel(
    const float* __restrict__ x, float* __restrict__ ftok) {
    const int r = blockIdx.x;
    const int pair = r >> 8, pidx = r & 255;
    const int srow = pair * 512 + pidx;
    const int c = threadIdx.x * 4;
    *(float4*)(ftok + (size_t)r * DMODEL + c) = *(const float4*)(x + (size_t)srow * DMODEL + c);
}

__global__ __launch_bounds__(192) void depatch_kernel(
    const float* __restrict__ pbuf, float* __restrict__ out) {
    const int r = blockIdx.x;
    const int tid = threadIdx.x;
    const int pair = r >> 8, pidx = r & 255;
    const int i = pidx >> 4, j = pidx & 15;
    const int cc = tid >> 6, a = (tid >> 3) & 7, b = tid & 7;
    out[((size_t)(pair * 3 + cc) * 128 + (i * 8 + a)) * 128 + (j * 8 + b)] =
        pbuf[(size_t)r * PIN + tid];
}

// ---------------- launcher ----------------
extern "C" void kernel_launch(void* const* d_in, const int* in_sizes, int n_in,
                              void* d_out, int out_size, void* d_ws, size_t ws_size,
                              hipStream_t stream) {
    const float* f     = (const float*)d_in[0];
    const float* g     = (const float*)d_in[1];
    const float* preW  = (const float*)d_in[2];
    const float* preb  = (const float*)d_in[3];
    const float* postW = (const float*)d_in[4];
    const float* postb = (const float*)d_in[5];
    const float* ppos  = (const float*)d_in[6];
    const float* fpos  = (const float*)d_in[7];
    const float* Wqkv  = (const float*)d_in[8];
    const float* bqkv  = (const float*)d_in[9];
    const float* Wo    = (const float*)d_in[10];
    const float* bo    = (const float*)d_in[11];
    const float* ln1s  = (const float*)d_in[12];
    const float* ln1b  = (const float*)d_in[13];
    const float* W1    = (const float*)d_in[14];
    const float* b1w   = (const float*)d_in[15];
    const float* W2    = (const float*)d_in[16];
    const float* b2w   = (const float*)d_in[17];
    const float* ln2s  = (const float*)d_in[18];
    const float* ln2b  = (const float*)d_in[19];
    float* out = (float*)d_out;

    // workspace layout (~91 MB): unionA is time-shared by {qkvbf | acts | ftok+pbuf}
    char* p = (char*)d_ws;
    float*  x      = (float*)p;   p += (size_t)NTOK * DMODEL * 4;   // 10.5 MB
    __bf16* hbufs  = (__bf16*)p;  p += (size_t)NTOK * 2048 * 2;     // 10.5 MB
    __bf16* obufs  = (__bf16*)p;  p += (size_t)NTOK * 2048 * 2;     // 10.5 MB
    char*   unionA = p;           p += (size_t)NTOK * 8192 * 2;     // 42 MB
    __bf16* wT     = (__bf16*)p;  p += (size_t)4096 * 2048 * 2;     // 16.8 MB (max weight)

    __bf16* qkvbf = (__bf16*)unionA;                      // 15.7 MB (dead after attn)
    __bf16* acts  = (__bf16*)unionA;                      // 42 MB  (MLP1 -> MLP2)
    float*  ftok  = (float*)unionA;                       // 5.2 MB (post-loop only)
    float*  pbuf  = (float*)(unionA + (size_t)1280 * DMODEL * 4);   // 1 MB

    patch_pre_kernel<<<NTOK / 4, 256, 0, stream>>>(f, g, preW, preb, ppos, fpos, x);

    for (int L = 0; L < 4; ++L) {
        ln_split_kernel<<<NTOK, 256, 0, stream>>>(x, ln1s + L * DMODEL, ln1b + L * DMODEL, hbufs);
        wprep_kernel<<<dim3(3072 / 32, 1024 / 32), 256, 0, stream>>>(
            Wqkv + (size_t)L * 1024 * 3072, wT, 1024, 3072);
        gemm_mfma<0><<<dim3(24, 20), 256, 0, stream>>>(
            hbufs, wT, bqkv + (size_t)L * 3072, nullptr, qkvbf, NTOK, 3072, 1024);
        attn_mfma<<<dim3(16, 40), 256, 0, stream>>>(qkvbf, obufs);
        wprep_kernel<<<dim3(1024 / 32, 1024 / 32), 256, 0, stream>>>(
            Wo + (size_t)L * 1024 * 1024, wT, 1024, 1024);
        gemm_mfma<1><<<dim3(8, 20), 256, 0, stream>>>(
            obufs, wT, bo + (size_t)L * DMODEL, x, nullptr, NTOK, 1024, 1024);
        ln_split_kernel<<<NTOK, 256, 0, stream>>>(x, ln2s + L * DMODEL, ln2b + L * DMODEL, hbufs);
        wprep_kernel<<<dim3(4096 / 32, 1024 / 32), 256, 0, stream>>>(
            W1 + (size_t)L * 1024 * 4096, wT, 1024, 4096);
        gemm_mfma<2><<<dim3(32, 20), 256, 0, stream>>>(
            hbufs, wT, b1w + (size_t)L * DFF, nullptr, acts, NTOK, 4096, 1024);
        wprep_kernel<<<dim3(1024 / 32, 4096 / 32), 256, 0, stream>>>(
            W2 + (size_t)L * 4096 * 1024, wT, 4096, 1024);
        gemm_mfma<1><<<dim3(8, 20), 256, 0, stream>>>(
            acts, wT, b2w + (size_t)L * DMODEL, x, nullptr, NTOK, 1024, 4096);
    }

    gather_f_kernel<<<1280, 256, 0, stream>>>(x, ftok);
    gemm64k<0><<<dim3(PIN / 64, 1280 / 64), 256, 0, stream>>>(
        ftok, postW, postb, nullptr, pbuf, 1280, PIN, 1024);
    depatch_kernel<<<1280, 192, 0, stream>>>(pbuf, out);
}

// Round 4
// 1739.960 us; speedup vs baseline: 3.3948x; 1.0723x over previous
//
#include <hip/hip_runtime.h>
#include <hip/hip_bf16.h>
#include <math.h>

#define DMODEL 1024
#define DFF    4096
#define NTOK   2560
#define PIN    192

typedef __attribute__((ext_vector_type(8))) __bf16 bf16x8;
typedef __attribute__((ext_vector_type(4))) __bf16 bf16x4;
typedef __attribute__((ext_vector_type(4))) float  f32x4;

#define MFMA16(a, b, c) __builtin_amdgcn_mfma_f32_16x16x32_bf16(a, b, c, 0, 0, 0)

__device__ __forceinline__ float gelu_f(float x) {
    const float x3 = x * x * x;
    return 0.5f * x * (1.0f + tanhf(0.7978845608028654f * (x + 0.044715f * x3)));
}

__device__ __forceinline__ void gload16(const void* g, void* l) {
    __builtin_amdgcn_global_load_lds((const __attribute__((address_space(1))) void*)g,
                                     (__attribute__((address_space(3))) void*)l, 16, 0, 0);
}

__device__ __forceinline__ void split_bf(float v, __bf16& hi, __bf16& lo) {
    hi = (__bf16)v;
    lo = (__bf16)(v - (float)hi);
}

// Split-swizzled activation layout ("SS layout"), used for every GEMM A/B operand:
// row r of K fp32 values -> K/32 blocks of 64 bf16 (128 B). Within a block, eight
// 16 B slots; logical slot sl (0-3 = hi k-chunks, 4-7 = lo k-chunks) stored at
// physical slot sl ^ (r & 7). GEMM stages blocks linearly with global_load_lds and
// reads fragments applying the same XOR -> conflict-free ds_read_b128.

// ---------------- patchify + pre_proj + pos enc (fp32, 4 tokens/block) ----------------
__global__ __launch_bounds__(256) void patch_pre_kernel(
    const float* __restrict__ f, const float* __restrict__ g,
    const float* __restrict__ preW, const float* __restrict__ preb,
    const float* __restrict__ ppos, const float* __restrict__ fpos,
    float* __restrict__ out) {
    const int s0  = blockIdx.x * 4;
    const int tid = threadIdx.x;
    const int n    = s0 >> 8;
    const int pair = n >> 1, t = n & 1;
    const float* src = t ? g : f;

    __shared__ float patch[4][PIN];
    for (int l = tid; l < 4 * PIN; l += 256) {
        const int tok = l / PIN, kk = l - tok * PIN;
        const int pidx = (s0 & 255) + tok;
        const int cc = kk >> 6, a = (kk >> 3) & 7, b = kk & 7;
        const int i = pidx >> 4, j = pidx & 15;
        patch[tok][kk] = src[((size_t)(pair * 3 + cc) * 128 + (i * 8 + a)) * 128 + (j * 8 + b)];
    }
    __syncthreads();

    const int n0 = tid * 4;
    float acc[4][4] = {};
    for (int k = 0; k < PIN; ++k) {
        const float4 w = *(const float4*)(preW + (size_t)k * DMODEL + n0);
#pragma unroll
        for (int tok = 0; tok < 4; ++tok) {
            const float pv = patch[tok][k];
            acc[tok][0] += pv * w.x; acc[tok][1] += pv * w.y;
            acc[tok][2] += pv * w.z; acc[tok][3] += pv * w.w;
        }
    }
    const float4 pb = *(const float4*)(preb + n0);
    const float4 fp = *(const float4*)(fpos + (size_t)n * DMODEL + n0);
#pragma unroll
    for (int tok = 0; tok < 4; ++tok) {
        const int pidx = (s0 & 255) + tok;
        const float4 pp = *(const float4*)(ppos + (size_t)pidx * DMODEL + n0);
        float4 o;
        o.x = acc[tok][0] + pb.x + pp.x + fp.x;
        o.y = acc[tok][1] + pb.y + pp.y + fp.y;
        o.z = acc[tok][2] + pb.z + pp.z + fp.z;
        o.w = acc[tok][3] + pb.w + pp.w + fp.w;
        *(float4*)(out + (size_t)(s0 + tok) * DMODEL + n0) = o;
    }
}

// ---------------- weight prep: W[K][N] fp32 -> WT (SS layout, rows = N) ----------------
__global__ __launch_bounds__(256) void wprep_kernel(
    const float* __restrict__ W, __bf16* __restrict__ WT, int K, int N) {
    const int n0 = blockIdx.x * 32, k0 = blockIdx.y * 32;
    const int tid = threadIdx.x;
    __shared__ float t[32][33];

    {
        const int kl = tid >> 3, nq = (tid & 7) * 4;
        const float4 v = *(const float4*)(W + (size_t)(k0 + kl) * N + n0 + nq);
        t[kl][nq] = v.x; t[kl][nq + 1] = v.y; t[kl][nq + 2] = v.z; t[kl][nq + 3] = v.w;
    }
    __syncthreads();

    const int nl = tid >> 3, kq = (tid & 7) * 4;
    const int n = n0 + nl;
    bf16x4 h4, l4;
#pragma unroll
    for (int i = 0; i < 4; ++i) {
        __bf16 hi, lo;
        split_bf(t[kq + i][nl], hi, lo);
        h4[i] = hi; l4[i] = lo;
    }
    const size_t base = (size_t)n * 2 * K + (size_t)(k0 >> 5) * 64 + (kq & 7);
    const int sl = kq >> 3, key = n & 7;
    *(bf16x4*)&WT[base + (size_t)((sl ^ key) << 3)]       = h4;
    *(bf16x4*)&WT[base + (size_t)(((sl | 4) ^ key) << 3)] = l4;
}

// ---------------- LayerNorm -> SS-layout split bf16 ----------------
__global__ __launch_bounds__(256) void ln_split_kernel(
    const float* __restrict__ x, const float* __restrict__ gam,
    const float* __restrict__ bet, __bf16* __restrict__ o) {
    const int row = blockIdx.x, tid = threadIdx.x;
    const float* xr = x + (size_t)row * DMODEL;
    const float4 v = *(const float4*)(xr + tid * 4);

    __shared__ float red[4];
    __shared__ float stat[2];

    float s = v.x + v.y + v.z + v.w;
#pragma unroll
    for (int off = 32; off; off >>= 1) s += __shfl_down(s, off, 64);
    if ((tid & 63) == 0) red[tid >> 6] = s;
    __syncthreads();
    if (tid == 0) stat[0] = (red[0] + red[1] + red[2] + red[3]) * (1.0f / DMODEL);
    __syncthreads();
    const float m = stat[0];
    const float dx = v.x - m, dy = v.y - m, dz = v.z - m, dw = v.w - m;
    float ss = dx * dx + dy * dy + dz * dz + dw * dw;
#pragma unroll
    for (int off = 32; off; off >>= 1) ss += __shfl_down(ss, off, 64);
    if ((tid & 63) == 0) red[tid >> 6] = ss;
    __syncthreads();
    if (tid == 0) stat[1] = rsqrtf((red[0] + red[1] + red[2] + red[3]) * (1.0f / DMODEL) + 1e-5f);
    __syncthreads();
    const float rstd = stat[1];

    const float4 gv = *(const float4*)(gam + tid * 4);
    const float4 bv = *(const float4*)(bet + tid * 4);
    float ov[4];
    ov[0] = dx * rstd * gv.x + bv.x;
    ov[1] = dy * rstd * gv.y + bv.y;
    ov[2] = dz * rstd * gv.z + bv.z;
    ov[3] = dw * rstd * gv.w + bv.w;

    bf16x4 h4, l4;
#pragma unroll
    for (int i = 0; i < 4; ++i) {
        __bf16 hi, lo;
        split_bf(ov[i], hi, lo);
        h4[i] = hi; l4[i] = lo;
    }
    const int k0 = tid * 4;
    const size_t base = (size_t)row * 2048 + (size_t)(k0 >> 5) * 64 + (k0 & 7);
    const int sl = (k0 >> 3) & 3, key = row & 7;
    *(bf16x4*)&o[base + (size_t)((sl ^ key) << 3)]       = h4;
    *(bf16x4*)&o[base + (size_t)(((sl | 4) ^ key) << 3)] = l4;
}

// ---------------- bf16x3 MFMA GEMM ----------------
// A: SS layout [M][2K]  B: SS layout [N][2K]
// EPI 0: bfout[M][N] = bf16(acc + bias)                 (QKV)
// EPI 1: resout[M][N] += acc + bias                     (residual add, splits=1)
// EPI 2: bfout = SS-layout split of gelu(acc + bias)    (MLP1)
// EPI 3: resout[z*M*N + rr*N + col] = acc               (split-K partial, fp32)
// gridDim.z = K-splits (only EPI 3 uses z > 1). XCD-bijective block swizzle
// (per-plane block count must be a multiple of 8).
template <int EPI>
__global__ __launch_bounds__(256) void gemm_mfma(
    const __bf16* __restrict__ A, const __bf16* __restrict__ B,
    const float* __restrict__ bias, float* __restrict__ resout,
    __bf16* __restrict__ bfout, int M, int N, int K) {
    __shared__ __bf16 sm[2][2][128 * 64];
    const int tid = threadIdx.x;
    const int w = tid >> 6, l = tid & 63;

    const int nwg = gridDim.x * gridDim.y;
    int bid = blockIdx.y * gridDim.x + blockIdx.x;
    bid = (bid & 7) * (nwg >> 3) + (bid >> 3);          // bijective (nwg % 8 == 0)
    const int bn = bid % gridDim.x, bm = bid / gridDim.x;

    const int kz = blockIdx.z;
    const int nkTot = K >> 5;
    const int nk  = nkTot / gridDim.z;
    const int kb0 = kz * nk;

    const int mat = w >> 1, half = w & 1;
    const size_t rowBytes = (size_t)K * 4;   // bytes per SS row (2K bf16)
    const char* gsrc = (const char*)(mat ? B : A)
        + (size_t)((mat ? bn : bm) * 128 + half * 64 + (l >> 3)) * rowBytes
        + (size_t)(l & 7) * 16;

    auto STAGE = [&](int buf, int kbAbs) {
        const char* s = gsrc + (size_t)kbAbs * 128;
#pragma unroll
        for (int it = 0; it < 8; ++it)
            gload16(s + (size_t)(it * 8) * rowBytes,
                    (void*)&sm[buf][mat][(size_t)(half * 64 + it * 8) * 64]);
    };

    f32x4 acc[4][4];
#pragma unroll
    for (int i = 0; i < 4; ++i)
#pragma unroll
        for (int j = 0; j < 4; ++j) acc[i][j] = f32x4{0.f, 0.f, 0.f, 0.f};

    const int lr = l & 15, lk = l >> 4;
    const int wr = (w >> 1) * 64, wc = (w & 1) * 64;

    STAGE(0, kb0);
    __syncthreads();

    for (int kb = 0; kb < nk; ++kb) {
        const int buf = kb & 1;
        if (kb + 1 < nk) STAGE(buf ^ 1, kb0 + kb + 1);

        const __bf16* As = sm[buf][0];
        const __bf16* Bs = sm[buf][1];
        bf16x8 ah[4], al[4], bh[4], bl[4];
#pragma unroll
        for (int i = 0; i < 4; ++i) {
            const int row = wr + i * 16 + lr, kx = row & 7;
            ah[i] = *(const bf16x8*)&As[(size_t)row * 64 + ((lk ^ kx) << 3)];
            al[i] = *(const bf16x8*)&As[(size_t)row * 64 + (((lk | 4) ^ kx) << 3)];
            const int col = wc + i * 16 + lr, ky = col & 7;
            bh[i] = *(const bf16x8*)&Bs[(size_t)col * 64 + ((lk ^ ky) << 3)];
            bl[i] = *(const bf16x8*)&Bs[(size_t)col * 64 + (((lk | 4) ^ ky) << 3)];
        }
#pragma unroll
        for (int i = 0; i < 4; ++i)
#pragma unroll
            for (int j = 0; j < 4; ++j) {
                acc[i][j] = MFMA16(ah[i], bh[j], acc[i][j]);
                acc[i][j] = MFMA16(al[i], bh[j], acc[i][j]);
                acc[i][j] = MFMA16(ah[i], bl[j], acc[i][j]);
            }
        __syncthreads();
    }

#pragma unroll
    for (int j = 0; j < 4; ++j) {
        const int col = bn * 128 + wc + j * 16 + lr;
        const float bv = (EPI == 3) ? 0.f : bias[col];
#pragma unroll
        for (int i = 0; i < 4; ++i) {
#pragma unroll
            for (int r = 0; r < 4; ++r) {
                const int rr = bm * 128 + wr + i * 16 + lk * 4 + r;
                const float v = acc[i][j][r] + bv;
                if (EPI == 0) {
                    bfout[(size_t)rr * N + col] = (__bf16)v;
                } else if (EPI == 1) {
                    resout[(size_t)rr * N + col] += v;
                } else if (EPI == 3) {
                    resout[((size_t)kz * M + rr) * N + col] = acc[i][j][r];
                } else {
                    const float gv2 = gelu_f(v);
                    __bf16 hi, lo;
                    split_bf(gv2, hi, lo);
                    const size_t base = (size_t)rr * 2 * N + (size_t)(col >> 5) * 64 + (col & 7);
                    const int sl = (col >> 3) & 3, kx = rr & 7;
                    bfout[base + (size_t)((sl ^ kx) << 3)]       = hi;
                    bfout[base + (size_t)(((sl | 4) ^ kx) << 3)] = lo;
                }
            }
        }
    }
}

// ---------------- split-K reduce: x += p0 + p1 + bias ----------------
__global__ __launch_bounds__(256) void reduce_splitk(
    const float* __restrict__ part, const float* __restrict__ bias,
    float* __restrict__ x, int MN, int N) {
    const int i = (blockIdx.x * 256 + threadIdx.x) * 4;
    if (i >= MN) return;
    const float4 p0 = *(const float4*)(part + i);
    const float4 p1 = *(const float4*)(part + (size_t)MN + i);
    const float4 bv = *(const float4*)(bias + (i & (N - 1)));
    float4 xv = *(float4*)(x + i);
    xv.x += p0.x + p1.x + bv.x;
    xv.y += p0.y + p1.y + bv.y;
    xv.z += p0.z + p1.z + bv.z;
    xv.w += p0.w + p1.w + bv.w;
    *(float4*)(x + i) = xv;
}

// ---------------- flash attention, bf16 MFMA 16x16x32, 4 waves x 16 queries ----------------
__global__ __launch_bounds__(256) void attn_mfma(
    const __bf16* __restrict__ qkv, __bf16* __restrict__ o) {
    // head-major XCD swizzle: XCD (lin & 7) owns head pair
    const int lin = blockIdx.y * gridDim.x + blockIdx.x;
    const int h  = ((lin & 7) << 1) | ((lin >> 3) & 1);
    const int qb = lin >> 4;
    const int tid = threadIdx.x;
    const int w = tid >> 6, l = tid & 63;
    const int lr = l & 15, lk = l >> 4;

    __shared__ __bf16 Ks[64 * 64];
    __shared__ __bf16 Vt[64 * 64];
    __shared__ __bf16 Ps[4][16 * 64];

    const int qrow = qb * 64 + w * 16 + lr;
    const __bf16* qsrc = qkv + (size_t)qrow * 3072 + h * 64 + lk * 8;
    const bf16x8 qf0 = *(const bf16x8*)qsrc;
    const bf16x8 qf1 = *(const bf16x8*)(qsrc + 32);

    f32x4 oacc[4];
#pragma unroll
    for (int i = 0; i < 4; ++i) oacc[i] = f32x4{0.f, 0.f, 0.f, 0.f};
    float mrow[4], lrow[4];
#pragma unroll
    for (int r = 0; r < 4; ++r) { mrow[r] = -3.0e38f; lrow[r] = 0.f; }

    const int skey = tid >> 2, dc = (tid & 3) * 16;
    const int nch = ((qb >> 2) + 1) * 4;

    for (int kc = 0; kc < nch; ++kc) {
        __syncthreads();
        {   // stage K (swizzled [key][d]) and V^T (swizzled [d][key])
            const __bf16* kp = qkv + (size_t)(kc * 64 + skey) * 3072 + 1024 + h * 64 + dc;
            const bf16x8 k0 = *(const bf16x8*)kp;
            const bf16x8 k1 = *(const bf16x8*)(kp + 8);
            const int sl0 = dc >> 3;
            *(bf16x8*)&Ks[skey * 64 + ((sl0 ^ (skey & 7)) << 3)]       = k0;
            *(bf16x8*)&Ks[skey * 64 + (((sl0 | 1) ^ (skey & 7)) << 3)] = k1;

            const __bf16* vp = kp + 1024;
            const bf16x8 v0 = *(const bf16x8*)vp;
            const bf16x8 v1 = *(const bf16x8*)(vp + 8);
#pragma unroll
            for (int e = 0; e < 8; ++e) {
                const int d0 = dc + e, d1 = dc + 8 + e;
                Vt[d0 * 64 + (((skey >> 3) ^ (d0 & 7)) << 3) + (skey & 7)] = v0[e];
                Vt[d1 * 64 + (((skey >> 3) ^ (d1 & 7)) << 3) + (skey & 7)] = v1[e];
            }
        }
        __syncthreads();

        // QK^T
        f32x4 sv[4];
#pragma unroll
        for (int j = 0; j < 4; ++j) {
            sv[j] = f32x4{0.f, 0.f, 0.f, 0.f};
            const int kb = j * 16 + lr, sw = kb & 7;
            const bf16x8 kb0 = *(const bf16x8*)&Ks[kb * 64 + ((lk ^ sw) << 3)];
            const bf16x8 kb1 = *(const bf16x8*)&Ks[kb * 64 + (((lk | 4) ^ sw) << 3)];
            sv[j] = MFMA16(qf0, kb0, sv[j]);
            sv[j] = MFMA16(qf1, kb1, sv[j]);
        }

        // online softmax (C layout: row = lk*4+r, col = j*16+lr)
#pragma unroll
        for (int r = 0; r < 4; ++r) {
            float cm = fmaxf(fmaxf(sv[0][r], sv[1][r]), fmaxf(sv[2][r], sv[3][r])) * 0.125f;
#pragma unroll
            for (int msk = 1; msk < 16; msk <<= 1) cm = fmaxf(cm, __shfl_xor(cm, msk, 64));
            const float nm = fmaxf(mrow[r], cm);
            const float sc = __expf(mrow[r] - nm);
            float rs = 0.f;
#pragma unroll
            for (int j = 0; j < 4; ++j) {
                const float p = __expf(sv[j][r] * 0.125f - nm);
                sv[j][r] = p;
                rs += p;
            }
#pragma unroll
            for (int msk = 1; msk < 16; msk <<= 1) rs += __shfl_xor(rs, msk, 64);
            lrow[r] = lrow[r] * sc + rs;
            mrow[r] = nm;
#pragma unroll
            for (int db = 0; db < 4; ++db) oacc[db][r] *= sc;
        }

        // P -> per-wave LDS (swizzled [q][key]); same-wave in-order DS, no barrier
#pragma unroll
        for (int j = 0; j < 4; ++j)
#pragma unroll
            for (int r = 0; r < 4; ++r) {
                const int q = lk * 4 + r, key = j * 16 + lr;
                Ps[w][q * 64 + (((key >> 3) ^ (q & 7)) << 3) + (key & 7)] = (__bf16)sv[j][r];
            }
        asm volatile("" ::: "memory");

        // PV
#pragma unroll
        for (int db = 0; db < 4; ++db) {
            const int d = db * 16 + lr, dw2 = d & 7;
#pragma unroll
            for (int kk = 0; kk < 2; ++kk) {
                const int sl = kk * 4 + lk;
                const bf16x8 pa = *(const bf16x8*)&Ps[w][lr * 64 + ((sl ^ (lr & 7)) << 3)];
                const bf16x8 vb = *(const bf16x8*)&Vt[d * 64 + ((sl ^ dw2) << 3)];
                oacc[db] = MFMA16(pa, vb, oacc[db]);
            }
        }
    }

    float inv[4];
#pragma unroll
    for (int r = 0; r < 4; ++r) inv[r] = 1.0f / lrow[r];

#pragma unroll
    for (int db = 0; db < 4; ++db)
#pragma unroll
        for (int r = 0; r < 4; ++r) {
            const float v = oacc[db][r] * inv[r];
            const int rr = qb * 64 + w * 16 + lk * 4 + r;
            const int col = h * 64 + db * 16 + lr;
            __bf16 hi, lo;
            split_bf(v, hi, lo);
            const size_t base = (size_t)rr * 2048 + (size_t)(col >> 5) * 64 + (col & 7);
            const int sl = (col >> 3) & 3, kx = rr & 7;
            o[base + (size_t)((sl ^ kx) << 3)]       = hi;
            o[base + (size_t)(((sl | 4) ^ kx) << 3)] = lo;
        }
}

// ---------------- fp32 SGEMM 64x64 (post-proj only) ----------------
template <int EPI>
__global__ __launch_bounds__(256) void gemm64k(
    const float* __restrict__ A, const float* __restrict__ B,
    const float* __restrict__ bias, const float* __restrict__ res,
    float* __restrict__ C, int M, int N, int K) {
    __shared__ float As[16][64];
    __shared__ float Bs[16][64];
    const int tid = threadIdx.x;
    const int bm = blockIdx.y, bn = blockIdx.x;
    const int tx = tid & 15, ty = tid >> 4;

    float acc[4][4] = {};

    const int am = tid & 63, ka = (tid >> 6) * 4;
    const int bnn = tid & 63, kb = (tid >> 6) * 4;
    const float* Ap = A + (size_t)(bm * 64 + am) * K + ka;
    const float* Bp = B + (size_t)kb * N + bn * 64 + bnn;

    for (int kt = 0; kt < K; kt += 16) {
        const float4 a0 = *(const float4*)Ap;
        const float b0 = Bp[0];
        const float b1 = Bp[(size_t)N];
        const float b2 = Bp[(size_t)2 * N];
        const float b3 = Bp[(size_t)3 * N];
        __syncthreads();
        As[ka + 0][am] = a0.x; As[ka + 1][am] = a0.y; As[ka + 2][am] = a0.z; As[ka + 3][am] = a0.w;
        Bs[kb + 0][bnn] = b0; Bs[kb + 1][bnn] = b1; Bs[kb + 2][bnn] = b2; Bs[kb + 3][bnn] = b3;
        __syncthreads();
#pragma unroll
        for (int kk = 0; kk < 16; ++kk) {
            float a[4], b[4];
            *(float4*)&a[0] = *(const float4*)&As[kk][ty * 4];
            *(float4*)&b[0] = *(const float4*)&Bs[kk][tx * 4];
#pragma unroll
            for (int i = 0; i < 4; ++i)
#pragma unroll
                for (int j = 0; j < 4; ++j)
                    acc[i][j] += a[i] * b[j];
        }
        Ap += 16;
        Bp += (size_t)16 * N;
    }

    const int col0 = bn * 64 + tx * 4;
    const float4 bv = *(const float4*)(bias + col0);
    const float* bvp = (const float*)&bv;
#pragma unroll
    for (int i = 0; i < 4; ++i) {
        const int row = bm * 64 + ty * 4 + i;
        float o0[4];
#pragma unroll
        for (int j = 0; j < 4; ++j) o0[j] = acc[i][j] + bvp[j];
        if (EPI == 1) {
            const float4 r0 = *(const float4*)(res + (size_t)row * N + col0);
            o0[0] += r0.x; o0[1] += r0.y; o0[2] += r0.z; o0[3] += r0.w;
        }
        *(float4*)(C + (size_t)row * N + col0) = make_float4(o0[0], o0[1], o0[2], o0[3]);
    }
}

// ---------------- output-side gather / scatter ----------------
__global__ __launch_bounds__(256) void gather_f_kernel(
    const float* __restrict__ x, float* __restrict__ ftok) {
    const int r = blockIdx.x;
    const int pair = r >> 8, pidx = r & 255;
    const int srow = pair * 512 + pidx;
    const int c = threadIdx.x * 4;
    *(float4*)(ftok + (size_t)r * DMODEL + c) = *(const float4*)(x + (size_t)srow * DMODEL + c);
}

__global__ __launch_bounds__(192) void depatch_kernel(
    const float* __restrict__ pbuf, float* __restrict__ out) {
    const int r = blockIdx.x;
    const int tid = threadIdx.x;
    const int pair = r >> 8, pidx = r & 255;
    const int i = pidx >> 4, j = pidx & 15;
    const int cc = tid >> 6, a = (tid >> 3) & 7, b = tid & 7;
    out[((size_t)(pair * 3 + cc) * 128 + (i * 8 + a)) * 128 + (j * 8 + b)] =
        pbuf[(size_t)r * PIN + tid];
}

// ---------------- launcher ----------------
extern "C" void kernel_launch(void* const* d_in, const int* in_sizes, int n_in,
                              void* d_out, int out_size, void* d_ws, size_t ws_size,
                              hipStream_t stream) {
    const float* f     = (const float*)d_in[0];
    const float* g     = (const float*)d_in[1];
    const float* preW  = (const float*)d_in[2];
    const float* preb  = (const float*)d_in[3];
    const float* postW = (const float*)d_in[4];
    const float* postb = (const float*)d_in[5];
    const float* ppos  = (const float*)d_in[6];
    const float* fpos  = (const float*)d_in[7];
    const float* Wqkv  = (const float*)d_in[8];
    const float* bqkv  = (const float*)d_in[9];
    const float* Wo    = (const float*)d_in[10];
    const float* bo    = (const float*)d_in[11];
    const float* ln1s  = (const float*)d_in[12];
    const float* ln1b  = (const float*)d_in[13];
    const float* W1    = (const float*)d_in[14];
    const float* b1w   = (const float*)d_in[15];
    const float* W2    = (const float*)d_in[16];
    const float* b2w   = (const float*)d_in[17];
    const float* ln2s  = (const float*)d_in[18];
    const float* ln2b  = (const float*)d_in[19];
    float* out = (float*)d_out;

    // workspace layout (~91 MB): unionA time-shared by {qkvbf | O-proj partials | acts | ftok+pbuf}
    // hbufs+obufs (contiguous 21 MB) time-shared with MLP2 split-K partials.
    char* p = (char*)d_ws;
    float*  x      = (float*)p;   p += (size_t)NTOK * DMODEL * 4;   // 10.5 MB
    __bf16* hbufs  = (__bf16*)p;  p += (size_t)NTOK * 2048 * 2;     // 10.5 MB
    __bf16* obufs  = (__bf16*)p;  p += (size_t)NTOK * 2048 * 2;     // 10.5 MB
    char*   unionA = p;           p += (size_t)NTOK * 8192 * 2;     // 42 MB
    __bf16* wT     = (__bf16*)p;  p += (size_t)4096 * 2048 * 2;     // 16.8 MB

    __bf16* qkvbf = (__bf16*)unionA;                      // dead after attn
    float*  partO = (float*)unionA;                       // O-proj partials (2 planes, 21 MB)
    __bf16* acts  = (__bf16*)unionA;                      // MLP1 -> MLP2 (42 MB)
    float*  partM = (float*)hbufs;                        // MLP2 partials (2 planes = hbufs+obufs)
    float*  ftok  = (float*)unionA;                       // post-loop only
    float*  pbuf  = (float*)(unionA + (size_t)1280 * DMODEL * 4);

    patch_pre_kernel<<<NTOK / 4, 256, 0, stream>>>(f, g, preW, preb, ppos, fpos, x);

    for (int L = 0; L < 4; ++L) {
        ln_split_kernel<<<NTOK, 256, 0, stream>>>(x, ln1s + L * DMODEL, ln1b + L * DMODEL, hbufs);
        wprep_kernel<<<dim3(3072 / 32, 1024 / 32), 256, 0, stream>>>(
            Wqkv + (size_t)L * 1024 * 3072, wT, 1024, 3072);
        gemm_mfma<0><<<dim3(24, 20), 256, 0, stream>>>(
            hbufs, wT, bqkv + (size_t)L * 3072, nullptr, qkvbf, NTOK, 3072, 1024);
        attn_mfma<<<dim3(16, 40), 256, 0, stream>>>(qkvbf, obufs);
        wprep_kernel<<<dim3(1024 / 32, 1024 / 32), 256, 0, stream>>>(
            Wo + (size_t)L * 1024 * 1024, wT, 1024, 1024);
        gemm_mfma<3><<<dim3(8, 20, 2), 256, 0, stream>>>(
            obufs, wT, nullptr, partO, nullptr, NTOK, 1024, 1024);
        reduce_splitk<<<NTOK, 256, 0, stream>>>(partO, bo + (size_t)L * DMODEL, x,
                                                NTOK * DMODEL, DMODEL);
        ln_split_kernel<<<NTOK, 256, 0, stream>>>(x, ln2s + L * DMODEL, ln2b + L * DMODEL, hbufs);
        wprep_kernel<<<dim3(4096 / 32, 1024 / 32), 256, 0, stream>>>(
            W1 + (size_t)L * 1024 * 4096, wT, 1024, 4096);
        gemm_mfma<2><<<dim3(32, 20), 256, 0, stream>>>(
            hbufs, wT, b1w + (size_t)L * DFF, nullptr, acts, NTOK, 4096, 1024);
        wprep_kernel<<<dim3(1024 / 32, 4096 / 32), 256, 0, stream>>>(
            W2 + (size_t)L * 4096 * 1024, wT, 4096, 1024);
        gemm_mfma<3><<<dim3(8, 20, 2), 256, 0, stream>>>(
            acts, wT, nullptr, partM, nullptr, NTOK, 1024, 4096);
        reduce_splitk<<<NTOK, 256, 0, stream>>>(partM, b2w + (size_t)L * DMODEL, x,
                                                NTOK * DMODEL, DMODEL);
    }

    gather_f_kernel<<<1280, 256, 0, stream>>>(x, ftok);
    gemm64k<0><<<dim3(PIN / 64, 1280 / 64), 256, 0, stream>>>(
        ftok, postW, postb, nullptr, pbuf, 1280, PIN, 1024);
    depatch_kernel<<<1280, 192, 0, stream>>>(pbuf, out);
}

// Round 7
// 1660.897 us; speedup vs baseline: 3.5564x; 1.0476x over previous
//
#include <hip/hip_runtime.h>
#include <hip/hip_bf16.h>
#include <math.h>

#define DMODEL 1024
#define DFF    4096
#define NTOK   2560
#define PIN    192

typedef __attribute__((ext_vector_type(8))) __bf16 bf16x8;
typedef __attribute__((ext_vector_type(4))) __bf16 bf16x4;
typedef __attribute__((ext_vector_type(4))) float  f32x4;

#define MFMA16(a, b, c) __builtin_amdgcn_mfma_f32_16x16x32_bf16(a, b, c, 0, 0, 0)

__device__ __forceinline__ float gelu_f(float x) {
    const float x3 = x * x * x;
    return 0.5f * x * (1.0f + tanhf(0.7978845608028654f * (x + 0.044715f * x3)));
}

__device__ __forceinline__ void gload16(const void* g, void* l) {
    __builtin_amdgcn_global_load_lds((const __attribute__((address_space(1))) void*)g,
                                     (__attribute__((address_space(3))) void*)l, 16, 0, 0);
}

__device__ __forceinline__ void split_bf(float v, __bf16& hi, __bf16& lo) {
    hi = (__bf16)v;
    lo = (__bf16)(v - (float)hi);
}

// Split-swizzled activation layout ("SS layout") for GEMM A/B operands: row r of
// K fp32 values -> K/32 blocks of 64 bf16 (128 B), eight 16 B slots; logical slot
// sl (0-3 hi, 4-7 lo) stored at physical slot sl ^ (r & 7). Staged linearly with
// global_load_lds, read back with the same XOR -> conflict-free ds_read_b128.

// ---------------- patchify + pre_proj + pos enc (fp32, 4 tokens/block) ----------------
__global__ __launch_bounds__(256) void patch_pre_kernel(
    const float* __restrict__ f, const float* __restrict__ g,
    const float* __restrict__ preW, const float* __restrict__ preb,
    const float* __restrict__ ppos, const float* __restrict__ fpos,
    float* __restrict__ out) {
    const int s0  = blockIdx.x * 4;
    const int tid = threadIdx.x;
    const int n    = s0 >> 8;
    const int pair = n >> 1, t = n & 1;
    const float* src = t ? g : f;

    __shared__ float patch[4][PIN];
    for (int l = tid; l < 4 * PIN; l += 256) {
        const int tok = l / PIN, kk = l - tok * PIN;
        const int pidx = (s0 & 255) + tok;
        const int cc = kk >> 6, a = (kk >> 3) & 7, b = kk & 7;
        const int i = pidx >> 4, j = pidx & 15;
        patch[tok][kk] = src[((size_t)(pair * 3 + cc) * 128 + (i * 8 + a)) * 128 + (j * 8 + b)];
    }
    __syncthreads();

    const int n0 = tid * 4;
    float acc[4][4] = {};
    for (int k = 0; k < PIN; ++k) {
        const float4 w = *(const float4*)(preW + (size_t)k * DMODEL + n0);
#pragma unroll
        for (int tok = 0; tok < 4; ++tok) {
            const float pv = patch[tok][k];
            acc[tok][0] += pv * w.x; acc[tok][1] += pv * w.y;
            acc[tok][2] += pv * w.z; acc[tok][3] += pv * w.w;
        }
    }
    const float4 pb = *(const float4*)(preb + n0);
    const float4 fp = *(const float4*)(fpos + (size_t)n * DMODEL + n0);
#pragma unroll
    for (int tok = 0; tok < 4; ++tok) {
        const int pidx = (s0 & 255) + tok;
        const float4 pp = *(const float4*)(ppos + (size_t)pidx * DMODEL + n0);
        float4 o;
        o.x = acc[tok][0] + pb.x + pp.x + fp.x;
        o.y = acc[tok][1] + pb.y + pp.y + fp.y;
        o.z = acc[tok][2] + pb.z + pp.z + fp.z;
        o.w = acc[tok][3] + pb.w + pp.w + fp.w;
        *(float4*)(out + (size_t)(s0 + tok) * DMODEL + n0) = o;
    }
}

// ---------------- weight prep: W[K][N] fp32 -> WT (SS layout, rows = N) ----------------
__global__ __launch_bounds__(256) void wprep_kernel(
    const float* __restrict__ W, __bf16* __restrict__ WT, int K, int N) {
    const int n0 = blockIdx.x * 32, k0 = blockIdx.y * 32;
    const int tid = threadIdx.x;
    __shared__ float t[32][33];

    {
        const int kl = tid >> 3, nq = (tid & 7) * 4;
        const float4 v = *(const float4*)(W + (size_t)(k0 + kl) * N + n0 + nq);
        t[kl][nq] = v.x; t[kl][nq + 1] = v.y; t[kl][nq + 2] = v.z; t[kl][nq + 3] = v.w;
    }
    __syncthreads();

    const int nl = tid >> 3, kq = (tid & 7) * 4;
    const int n = n0 + nl;
    bf16x4 h4, l4;
#pragma unroll
    for (int i = 0; i < 4; ++i) {
        __bf16 hi, lo;
        split_bf(t[kq + i][nl], hi, lo);
        h4[i] = hi; l4[i] = lo;
    }
    const size_t base = (size_t)n * 2 * K + (size_t)(k0 >> 5) * 64 + (kq & 7);
    const int sl = kq >> 3, key = n & 7;
    *(bf16x4*)&WT[base + (size_t)((sl ^ key) << 3)]       = h4;
    *(bf16x4*)&WT[base + (size_t)(((sl | 4) ^ key) << 3)] = l4;
}

// ---------------- LayerNorm -> SS-layout split bf16 ----------------
__global__ __launch_bounds__(256) void ln_split_kernel(
    const float* __restrict__ x, const float* __restrict__ gam,
    const float* __restrict__ bet, __bf16* __restrict__ o) {
    const int row = blockIdx.x, tid = threadIdx.x;
    const float* xr = x + (size_t)row * DMODEL;
    const float4 v = *(const float4*)(xr + tid * 4);

    __shared__ float red[4];
    __shared__ float stat[2];

    float s = v.x + v.y + v.z + v.w;
#pragma unroll
    for (int off = 32; off; off >>= 1) s += __shfl_down(s, off, 64);
    if ((tid & 63) == 0) red[tid >> 6] = s;
    __syncthreads();
    if (tid == 0) stat[0] = (red[0] + red[1] + red[2] + red[3]) * (1.0f / DMODEL);
    __syncthreads();
    const float m = stat[0];
    const float dx = v.x - m, dy = v.y - m, dz = v.z - m, dw = v.w - m;
    float ss = dx * dx + dy * dy + dz * dz + dw * dw;
#pragma unroll
    for (int off = 32; off; off >>= 1) ss += __shfl_down(ss, off, 64);
    if ((tid & 63) == 0) red[tid >> 6] = ss;
    __syncthreads();
    if (tid == 0) stat[1] = rsqrtf((red[0] + red[1] + red[2] + red[3]) * (1.0f / DMODEL) + 1e-5f);
    __syncthreads();
    const float rstd = stat[1];

    const float4 gv = *(const float4*)(gam + tid * 4);
    const float4 bv = *(const float4*)(bet + tid * 4);
    float ov[4];
    ov[0] = dx * rstd * gv.x + bv.x;
    ov[1] = dy * rstd * gv.y + bv.y;
    ov[2] = dz * rstd * gv.z + bv.z;
    ov[3] = dw * rstd * gv.w + bv.w;

    bf16x4 h4, l4;
#pragma unroll
    for (int i = 0; i < 4; ++i) {
        __bf16 hi, lo;
        split_bf(ov[i], hi, lo);
        h4[i] = hi; l4[i] = lo;
    }
    const int k0 = tid * 4;
    const size_t base = (size_t)row * 2048 + (size_t)(k0 >> 5) * 64 + (k0 & 7);
    const int sl = (k0 >> 3) & 3, key = row & 7;
    *(bf16x4*)&o[base + (size_t)((sl ^ key) << 3)]       = h4;
    *(bf16x4*)&o[base + (size_t)(((sl | 4) ^ key) << 3)] = l4;
}

// ---------------- bf16x3 MFMA GEMM ----------------
// EPI 0: QKV — Q,K cols -> bfout[tok][2048]; V cols -> vtout[chunk][h][d][pi(tok)]
// EPI 1: resout[M][N] += acc + bias
// EPI 2: bfout = SS-layout split of gelu(acc + bias)    (MLP1)
// EPI 3: resout[z*M*N + rr*N + col] = acc               (split-K partial)
template <int EPI>
__global__ __launch_bounds__(256) void gemm_mfma(
    const __bf16* __restrict__ A, const __bf16* __restrict__ B,
    const float* __restrict__ bias, float* __restrict__ resout,
    __bf16* __restrict__ bfout, __bf16* __restrict__ vtout, int M, int N, int K) {
    __shared__ __bf16 sm[2][2][128 * 64];
    const int tid = threadIdx.x;
    const int w = tid >> 6, l = tid & 63;

    const int nwg = gridDim.x * gridDim.y;
    int bid = blockIdx.y * gridDim.x + blockIdx.x;
    bid = (bid & 7) * (nwg >> 3) + (bid >> 3);          // bijective (nwg % 8 == 0)
    const int bn = bid % gridDim.x, bm = bid / gridDim.x;

    const int kz = blockIdx.z;
    const int nkTot = K >> 5;
    const int nk  = nkTot / gridDim.z;
    const int kb0 = kz * nk;

    const int mat = w >> 1, half = w & 1;
    const size_t rowBytes = (size_t)K * 4;   // bytes per SS row (2K bf16)
    const char* gsrc = (const char*)(mat ? B : A)
        + (size_t)((mat ? bn : bm) * 128 + half * 64 + (l >> 3)) * rowBytes
        + (size_t)(l & 7) * 16;

    auto STAGE = [&](int buf, int kbAbs) {
        const char* s = gsrc + (size_t)kbAbs * 128;
#pragma unroll
        for (int it = 0; it < 8; ++it)
            gload16(s + (size_t)(it * 8) * rowBytes,
                    (void*)&sm[buf][mat][(size_t)(half * 64 + it * 8) * 64]);
    };

    f32x4 acc[4][4];
#pragma unroll
    for (int i = 0; i < 4; ++i)
#pragma unroll
        for (int j = 0; j < 4; ++j) acc[i][j] = f32x4{0.f, 0.f, 0.f, 0.f};

    const int lr = l & 15, lk = l >> 4;
    const int wr = (w >> 1) * 64, wc = (w & 1) * 64;

    STAGE(0, kb0);
    __syncthreads();

    for (int kb = 0; kb < nk; ++kb) {
        const int buf = kb & 1;
        if (kb + 1 < nk) STAGE(buf ^ 1, kb0 + kb + 1);

        const __bf16* As = sm[buf][0];
        const __bf16* Bs = sm[buf][1];
        bf16x8 ah[4], al[4], bh[4], bl[4];
#pragma unroll
        for (int i = 0; i < 4; ++i) {
            const int row = wr + i * 16 + lr, kx = row & 7;
            ah[i] = *(const bf16x8*)&As[(size_t)row * 64 + ((lk ^ kx) << 3)];
            al[i] = *(const bf16x8*)&As[(size_t)row * 64 + (((lk | 4) ^ kx) << 3)];
            const int col = wc + i * 16 + lr, ky = col & 7;
            bh[i] = *(const bf16x8*)&Bs[(size_t)col * 64 + ((lk ^ ky) << 3)];
            bl[i] = *(const bf16x8*)&Bs[(size_t)col * 64 + (((lk | 4) ^ ky) << 3)];
        }
#pragma unroll
        for (int i = 0; i < 4; ++i)
#pragma unroll
            for (int j = 0; j < 4; ++j) {
                acc[i][j] = MFMA16(ah[i], bh[j], acc[i][j]);
                acc[i][j] = MFMA16(al[i], bh[j], acc[i][j]);
                acc[i][j] = MFMA16(ah[i], bl[j], acc[i][j]);
            }
        __syncthreads();
    }

#pragma unroll
    for (int j = 0; j < 4; ++j) {
        const int col = bn * 128 + wc + j * 16 + lr;
        const float bv = (EPI == 3) ? 0.f : bias[col];
#pragma unroll
        for (int i = 0; i < 4; ++i) {
#pragma unroll
            for (int r = 0; r < 4; ++r) {
                const int rr = bm * 128 + wr + i * 16 + lk * 4 + r;
                const float v = acc[i][j][r] + bv;
                if (EPI == 0) {
                    if (col < 2048) {
                        bfout[(size_t)rr * 2048 + col] = (__bf16)v;
                    } else {
                        const int hv = col - 2048, hh = hv >> 6, dd = hv & 63;
                        const int tok = rr & 127, chn = rr >> 7;
                        const int tokp = (tok & 15) * 8 + (tok >> 4);
                        vtout[(((size_t)chn * 16 + hh) * 64 + dd) * 128 + tokp] = (__bf16)v;
                    }
                } else if (EPI == 1) {
                    resout[(size_t)rr * N + col] += v;
                } else if (EPI == 3) {
                    resout[((size_t)kz * M + rr) * N + col] = acc[i][j][r];
                } else {
                    const float gv2 = gelu_f(v);
                    __bf16 hi, lo;
                    split_bf(gv2, hi, lo);
                    const size_t base = (size_t)rr * 2 * N + (size_t)(col >> 5) * 64 + (col & 7);
                    const int sl = (col >> 3) & 3, kx = rr & 7;
                    bfout[base + (size_t)((sl ^ kx) << 3)]       = hi;
                    bfout[base + (size_t)(((sl | 4) ^ kx) << 3)] = lo;
                }
            }
        }
    }
}

// ---------------- split-K reduce: x += p0 + p1 + bias ----------------
__global__ __launch_bounds__(256) void reduce_splitk(
    const float* __restrict__ part, const float* __restrict__ bias,
    float* __restrict__ x, int MN, int N) {
    const int i = (blockIdx.x * 256 + threadIdx.x) * 4;
    if (i >= MN) return;
    const float4 p0 = *(const float4*)(part + i);
    const float4 p1 = *(const float4*)(part + (size_t)MN + i);
    const float4 bv = *(const float4*)(bias + (i & (N - 1)));
    float4 xv = *(float4*)(x + i);
    xv.x += p0.x + p1.x + bv.x;
    xv.y += p0.y + p1.y + bv.y;
    xv.z += p0.z + p1.z + bv.z;
    xv.w += p0.w + p1.w + bv.w;
    *(float4*)(x + i) = xv;
}

// ---------------- flash attention: 128-key chunks, vectorized staging, MFMA ----------------
// qk: [tok][2048] bf16 (Q | K per head).  vt: [chunk20][h16][d64][pi(tok128)] bf16.
// pi(t) = (t&15)*8 + (t>>4) applied consistently to V k-index and P k-index (cancels).
__global__ __launch_bounds__(256) void attn_mfma(
    const __bf16* __restrict__ qk, const __bf16* __restrict__ vt,
    __bf16* __restrict__ o) {
    const int lin = blockIdx.y * gridDim.x + blockIdx.x;
    const int h  = ((lin & 7) << 1) | ((lin >> 3) & 1);   // head pair per XCD
    const int qb = 39 - (lin >> 4);                        // longest blocks first
    const int tid = threadIdx.x;
    const int w = tid >> 6, l = tid & 63;
    const int lr = l & 15, lk = l >> 4;

    __shared__ __bf16 Ks[128 * 64];    // [key][d]  8 slots/row, sl ^ (key&7)
    __shared__ __bf16 Vs[64 * 128];    // [d][k']  16 slots/row, sl ^ (d&15)
    __shared__ __bf16 Ps[4][16 * 128]; // per-wave [q][k'] 16 slots/row, sl ^ q

    const f32x4 Z4 = {0.f, 0.f, 0.f, 0.f};

    // Q fragments, pre-scaled by 0.125 (exact in bf16)
    const int qrow = qb * 64 + w * 16 + lr;
    const __bf16* qsrc = qk + (size_t)qrow * 2048 + h * 64 + lk * 8;
    bf16x8 qf0 = *(const bf16x8*)qsrc;
    bf16x8 qf1 = *(const bf16x8*)(qsrc + 32);
#pragma unroll
    for (int e = 0; e < 8; ++e) {
        qf0[e] = (__bf16)((float)qf0[e] * 0.125f);
        qf1[e] = (__bf16)((float)qf1[e] * 0.125f);
    }

    f32x4 oacc[4];
#pragma unroll
    for (int i = 0; i < 4; ++i) oacc[i] = Z4;
    float mrow[4], lrow[4];
#pragma unroll
    for (int r = 0; r < 4; ++r) { mrow[r] = -3.0e38f; lrow[r] = 0.f; }

    // staging assignments (per wave: K keys w*32..+31, V rows w*16..+15)
    const int kKey = w * 32 + (l >> 1), kHalf = l & 1;
    const int vD   = w * 16 + (l >> 2), vC4  = l & 3;

    const int nch = ((qb >> 2) + 1) * 2;   // 128-key chunks allowed

    for (int kc = 0; kc < nch; ++kc) {
        __syncthreads();
        {   // stage K[128][64] and V^T[64][128] with b128 writes
            const __bf16* kp = qk + (size_t)(kc * 128 + kKey) * 2048 + 1024 + h * 64 + kHalf * 32;
            bf16x8 kv0 = ((const bf16x8*)kp)[0];
            bf16x8 kv1 = ((const bf16x8*)kp)[1];
            bf16x8 kv2 = ((const bf16x8*)kp)[2];
            bf16x8 kv3 = ((const bf16x8*)kp)[3];
            const int ksw = kKey & 7;
            *(bf16x8*)&Ks[kKey * 64 + (((kHalf * 4 + 0) ^ ksw) << 3)] = kv0;
            *(bf16x8*)&Ks[kKey * 64 + (((kHalf * 4 + 1) ^ ksw) << 3)] = kv1;
            *(bf16x8*)&Ks[kKey * 64 + (((kHalf * 4 + 2) ^ ksw) << 3)] = kv2;
            *(bf16x8*)&Ks[kKey * 64 + (((kHalf * 4 + 3) ^ ksw) << 3)] = kv3;

            const __bf16* vp = vt + (((size_t)(kc * 16 + h) * 64 + vD) * 128) + vC4 * 32;
            bf16x8 vv0 = ((const bf16x8*)vp)[0];
            bf16x8 vv1 = ((const bf16x8*)vp)[1];
            bf16x8 vv2 = ((const bf16x8*)vp)[2];
            bf16x8 vv3 = ((const bf16x8*)vp)[3];
            const int vsw = vD & 15;
            *(bf16x8*)&Vs[vD * 128 + (((vC4 * 4 + 0) ^ vsw) << 3)] = vv0;
            *(bf16x8*)&Vs[vD * 128 + (((vC4 * 4 + 1) ^ vsw) << 3)] = vv1;
            *(bf16x8*)&Vs[vD * 128 + (((vC4 * 4 + 2) ^ vsw) << 3)] = vv2;
            *(bf16x8*)&Vs[vD * 128 + (((vC4 * 4 + 3) ^ vsw) << 3)] = vv3;
        }
        __syncthreads();

        // QK^T: lane holds S[q=lk*4+r][key=j*16+lr]
        f32x4 sv[8];
        __builtin_amdgcn_s_setprio(1);
#pragma unroll
        for (int j = 0; j < 8; ++j) {
            const int kb = j * 16 + lr, sw = kb & 7;
            const bf16x8 kb0 = *(const bf16x8*)&Ks[kb * 64 + ((lk ^ sw) << 3)];
            const bf16x8 kb1 = *(const bf16x8*)&Ks[kb * 64 + (((lk | 4) ^ sw) << 3)];
            sv[j] = MFMA16(qf0, kb0, Z4);
            sv[j] = MFMA16(qf1, kb1, sv[j]);
        }
        __builtin_amdgcn_s_setprio(0);

        // online softmax + P pack (k' = lr*8 + j  <=>  key = j*16 + lr)
#pragma unroll
        for (int r = 0; r < 4; ++r) {
            float cm = sv[0][r];
#pragma unroll
            for (int j = 1; j < 8; ++j) cm = fmaxf(cm, sv[j][r]);
#pragma unroll
            for (int msk = 1; msk < 16; msk <<= 1) cm = fmaxf(cm, __shfl_xor(cm, msk, 64));
            const float nm = fmaxf(mrow[r], cm);
            const float sc = __expf(mrow[r] - nm);
            float rs = 0.f;
            bf16x8 pv;
#pragma unroll
            for (int j = 0; j < 8; ++j) {
                const float p = __expf(sv[j][r] - nm);
                pv[j] = (__bf16)p;
                rs += p;
            }
#pragma unroll
            for (int msk = 1; msk < 16; msk <<= 1) rs += __shfl_xor(rs, msk, 64);
            lrow[r] = lrow[r] * sc + rs;
            mrow[r] = nm;
#pragma unroll
            for (int db = 0; db < 4; ++db) oacc[db][r] *= sc;
            const int q = lk * 4 + r;
            *(bf16x8*)&Ps[w][q * 128 + ((lr ^ q) << 3)] = pv;
        }
        asm volatile("" ::: "memory");

        // PV: O[q=lk*4+reg][d=db*16+lr] += P[q][k'] * Vs[d][k']
        bf16x8 pa[4];
#pragma unroll
        for (int ksl = 0; ksl < 4; ++ksl)
            pa[ksl] = *(const bf16x8*)&Ps[w][lr * 128 + (((ksl * 4 + lk) ^ lr) << 3)];
        __builtin_amdgcn_s_setprio(1);
#pragma unroll
        for (int db = 0; db < 4; ++db) {
            const int d = db * 16 + lr, dsw = d & 15;
#pragma unroll
            for (int ksl = 0; ksl < 4; ++ksl) {
                const bf16x8 vb = *(const bf16x8*)&Vs[d * 128 + (((ksl * 4 + lk) ^ dsw) << 3)];
                oacc[db] = MFMA16(pa[ksl], vb, oacc[db]);
            }
        }
        __builtin_amdgcn_s_setprio(0);
    }

    float inv[4];
#pragma unroll
    for (int r = 0; r < 4; ++r) inv[r] = 1.0f / lrow[r];

#pragma unroll
    for (int db = 0; db < 4; ++db)
#pragma unroll
        for (int r = 0; r < 4; ++r) {
            const float v = oacc[db][r] * inv[r];
            const int rr = qb * 64 + w * 16 + lk * 4 + r;
            const int col = h * 64 + db * 16 + lr;
            __bf16 hi, lo;
            split_bf(v, hi, lo);
            const size_t base = (size_t)rr * 2048 + (size_t)(col >> 5) * 64 + (col & 7);
            const int sl = (col >> 3) & 3, kx = rr & 7;
            o[base + (size_t)((sl ^ kx) << 3)]       = hi;
            o[base + (size_t)(((sl | 4) ^ kx) << 3)] = lo;
        }
}

// ---------------- fp32 SGEMM 64x64 (post-proj only) ----------------
template <int EPI>
__global__ __launch_bounds__(256) void gemm64k(
    const float* __restrict__ A, const float* __restrict__ B,
    const float* __restrict__ bias, const float* __restrict__ res,
    float* __restrict__ C, int M, int N, int K) {
    __shared__ float As[16][64];
    __shared__ float Bs[16][64];
    const int tid = threadIdx.x;
    const int bm = blockIdx.y, bn = blockIdx.x;
    const int tx = tid & 15, ty = tid >> 4;

    float acc[4][4] = {};

    const int am = tid & 63, ka = (tid >> 6) * 4;
    const int bnn = tid & 63, kb = (tid >> 6) * 4;
    const float* Ap = A + (size_t)(bm * 64 + am) * K + ka;
    const float* Bp = B + (size_t)kb * N + bn * 64 + bnn;

    for (int kt = 0; kt < K; kt += 16) {
        const float4 a0 = *(const float4*)Ap;
        const float b0 = Bp[0];
        const float b1 = Bp[(size_t)N];
        const float b2 = Bp[(size_t)2 * N];
        const float b3 = Bp[(size_t)3 * N];
        __syncthreads();
        As[ka + 0][am] = a0.x; As[ka + 1][am] = a0.y; As[ka + 2][am] = a0.z; As[ka + 3][am] = a0.w;
        Bs[kb + 0][bnn] = b0; Bs[kb + 1][bnn] = b1; Bs[kb + 2][bnn] = b2; Bs[kb + 3][bnn] = b3;
        __syncthreads();
#pragma unroll
        for (int kk = 0; kk < 16; ++kk) {
            float a[4], b[4];
            *(float4*)&a[0] = *(const float4*)&As[kk][ty * 4];
            *(float4*)&b[0] = *(const float4*)&Bs[kk][tx * 4];
#pragma unroll
            for (int i = 0; i < 4; ++i)
#pragma unroll
                for (int j = 0; j < 4; ++j)
                    acc[i][j] += a[i] * b[j];
        }
        Ap += 16;
        Bp += (size_t)16 * N;
    }

    const int col0 = bn * 64 + tx * 4;
    const float4 bv = *(const float4*)(bias + col0);
    const float* bvp = (const float*)&bv;
#pragma unroll
    for (int i = 0; i < 4; ++i) {
        const int row = bm * 64 + ty * 4 + i;
        float o0[4];
#pragma unroll
        for (int j = 0; j < 4; ++j) o0[j] = acc[i][j] + bvp[j];
        if (EPI == 1) {
            const float4 r0 = *(const float4*)(res + (size_t)row * N + col0);
            o0[0] += r0.x; o0[1] += r0.y; o0[2] += r0.z; o0[3] += r0.w;
        }
        *(float4*)(C + (size_t)row * N + col0) = make_float4(o0[0], o0[1], o0[2], o0[3]);
    }
}

// ---------------- output-side gather / scatter ----------------
__global__ __launch_bounds__(256) void gather_f_kernel(
    const float* __restrict__ x, float* __restrict__ ftok) {
    const int r = blockIdx.x;
    const int pair = r >> 8, pidx = r & 255;
    const int srow = pair * 512 + pidx;
    const int c = threadIdx.x * 4;
    *(float4*)(ftok + (size_t)r * DMODEL + c) = *(const float4*)(x + (size_t)srow * DMODEL + c);
}

__global__ __launch_bounds__(192) void depatch_kernel(
    const float* __restrict__ pbuf, float* __restrict__ out) {
    const int r = blockIdx.x;
    const int tid = threadIdx.x;
    const int pair = r >> 8, pidx = r & 255;
    const int i = pidx >> 4, j = pidx & 15;
    const int cc = tid >> 6, a = (tid >> 3) & 7, b = tid & 7;
    out[((size_t)(pair * 3 + cc) * 128 + (i * 8 + a)) * 128 + (j * 8 + b)] =
        pbuf[(size_t)r * PIN + tid];
}

// ---------------- launcher ----------------
extern "C" void kernel_launch(void* const* d_in, const int* in_sizes, int n_in,
                              void* d_out, int out_size, void* d_ws, size_t ws_size,
                              hipStream_t stream) {
    const float* f     = (const float*)d_in[0];
    const float* g     = (const float*)d_in[1];
    const float* preW  = (const float*)d_in[2];
    const float* preb  = (const float*)d_in[3];
    const float* postW = (const float*)d_in[4];
    const float* postb = (const float*)d_in[5];
    const float* ppos  = (const float*)d_in[6];
    const float* fpos  = (const float*)d_in[7];
    const float* Wqkv  = (const float*)d_in[8];
    const float* bqkv  = (const float*)d_in[9];
    const float* Wo    = (const float*)d_in[10];
    const float* bo    = (const float*)d_in[11];
    const float* ln1s  = (const float*)d_in[12];
    const float* ln1b  = (const float*)d_in[13];
    const float* W1    = (const float*)d_in[14];
    const float* b1w   = (const float*)d_in[15];
    const float* W2    = (const float*)d_in[16];
    const float* b2w   = (const float*)d_in[17];
    const float* ln2s  = (const float*)d_in[18];
    const float* ln2b  = (const float*)d_in[19];
    float* out = (float*)d_out;

    // workspace (~91 MB): unionA time-shared by {qk_bf+vt_bf | O-proj partials | acts | ftok+pbuf}
    // hbufs+obufs (contiguous 21 MB) time-shared with MLP2 split-K partials.
    char* p = (char*)d_ws;
    float*  x      = (float*)p;   p += (size_t)NTOK * DMODEL * 4;   // 10.5 MB
    __bf16* hbufs  = (__bf16*)p;  p += (size_t)NTOK * 2048 * 2;     // 10.5 MB
    __bf16* obufs  = (__bf16*)p;  p += (size_t)NTOK * 2048 * 2;     // 10.5 MB
    char*   unionA = p;           p += (size_t)NTOK * 8192 * 2;     // 42 MB
    __bf16* wT     = (__bf16*)p;  p += (size_t)4096 * 2048 * 2;     // 16.8 MB

    __bf16* qk_bf = (__bf16*)unionA;                                 // 10.5 MB
    __bf16* vt_bf = (__bf16*)(unionA + (size_t)NTOK * 2048 * 2);     // 5.25 MB
    float*  partO = (float*)unionA;                                  // 21 MB (after attn)
    __bf16* acts  = (__bf16*)unionA;                                 // 42 MB (MLP1->MLP2)
    float*  partM = (float*)hbufs;                                   // 21 MB (hbufs+obufs)
    float*  ftok  = (float*)unionA;                                  // post-loop
    float*  pbuf  = (float*)(unionA + (size_t)1280 * DMODEL * 4);

    patch_pre_kernel<<<NTOK / 4, 256, 0, stream>>>(f, g, preW, preb, ppos, fpos, x);

    for (int L = 0; L < 4; ++L) {
        ln_split_kernel<<<NTOK, 256, 0, stream>>>(x, ln1s + L * DMODEL, ln1b + L * DMODEL, hbufs);
        wprep_kernel<<<dim3(3072 / 32, 1024 / 32), 256, 0, stream>>>(
            Wqkv + (size_t)L * 1024 * 3072, wT, 1024, 3072);
        gemm_mfma<0><<<dim3(24, 20), 256, 0, stream>>>(
            hbufs, wT, bqkv + (size_t)L * 3072, nullptr, qk_bf, vt_bf, NTOK, 3072, 1024);
        attn_mfma<<<dim3(16, 40), 256, 0, stream>>>(qk_bf, vt_bf, obufs);
        wprep_kernel<<<dim3(1024 / 32, 1024 / 32), 256, 0, stream>>>(
            Wo + (size_t)L * 1024 * 1024, wT, 1024, 1024);
        gemm_mfma<3><<<dim3(8, 20, 2), 256, 0, stream>>>(
            obufs, wT, nullptr, partO, nullptr, nullptr, NTOK, 1024, 1024);
        reduce_splitk<<<NTOK, 256, 0, stream>>>(partO, bo + (size_t)L * DMODEL, x,
                                                NTOK * DMODEL, DMODEL);
        ln_split_kernel<<<NTOK, 256, 0, stream>>>(x, ln2s + L * DMODEL, ln2b + L * DMODEL, hbufs);
        wprep_kernel<<<dim3(4096 / 32, 1024 / 32), 256, 0, stream>>>(
            W1 + (size_t)L * 1024 * 4096, wT, 1024, 4096);
        gemm_mfma<2><<<dim3(32, 20), 256, 0, stream>>>(
            hbufs, wT, b1w + (size_t)L * DFF, nullptr, acts, nullptr, NTOK, 4096, 1024);
        wprep_kernel<<<dim3(1024 / 32, 4096 / 32), 256, 0, stream>>>(
            W2 + (size_t)L * 4096 * 1024, wT, 4096, 1024);
        gemm_mfma<3><<<dim3(8, 20, 2), 256, 0, stream>>>(
            acts, wT, nullptr, partM, nullptr, nullptr, NTOK, 1024, 4096);
        reduce_splitk<<<NTOK, 256, 0, stream>>>(partM, b2w + (size_t)L * DMODEL, x,
                                                NTOK * DMODEL, DMODEL);
    }

    gather_f_kernel<<<1280, 256, 0, stream>>>(x, ftok);
    gemm64k<0><<<dim3(PIN / 64, 1280 / 64), 256, 0, stream>>>(
        ftok, postW, postb, nullptr, pbuf, 1280, PIN, 1024);
    depatch_kernel<<<1280, 192, 0, stream>>>(pbuf, out);
}